// Round 4
// baseline (278.293 us; speedup 1.0000x reference)
//
#include <hip/hip_runtime.h>
#include <hip/hip_bf16.h>

// SelfAttention (channel attention) on MI355X. Inputs fp32, OUTPUT fp32,
// internal compute bf16 (threshold is sized for bf16).
// Pipeline: GN -> q,k 1x1 (stored transposed per batch) -> attn=q^T k (split-K)
//           -> softmax -> v 1x1 -> h2 = v attn^T -> out = x + h2 wp + bp (fp32).
// GEMMs: 128x128 tile, 4 waves, mfma_f32_16x16x32_bf16, reg-staged LDS.
// Workspace (peak 115 MB, overlays noted):
//   [0,2MB)    WT   : [2048][512] bf16 (q,k,v,p weights transposed, bf16-cast)
//   [2MB,+2KB) stats: [256] float2
//   [3,35MB)   h_gn : [32768][512] bf16      -> later h2 (h_gn dead after v GEMM)
//   [35,67MB)  qT   : [8][512][4096] bf16    -> later attn (qT dead after attn GEMM)
//   [67,99MB)  kT   : [8][512][4096] bf16    -> later vb (kT dead after attn GEMM)
//   [99,115MB) part : [2][8][512][512] f32 (split-K partials)

using bf16   = __bf16;
using bf16x8 = __attribute__((ext_vector_type(8))) __bf16;
using bf16x4 = __attribute__((ext_vector_type(4))) __bf16;
using f32x4  = __attribute__((ext_vector_type(4))) float;

#define DI __device__ __forceinline__

DI void zero_acc(f32x4 acc[4][4]) {
#pragma unroll
  for (int i = 0; i < 4; ++i)
#pragma unroll
    for (int j = 0; j < 4; ++j)
      acc[i][j] = (f32x4){0.f, 0.f, 0.f, 0.f};
}

// A: [>=128 rows, K] bf16 row-major (lda); B: same (ldb) == B^T form.
// 128x128 C-tile in acc: 4 waves, each owns a 64x64 quadrant = 4x4 frags of 16x16.
DI void gemm128_core(const bf16* __restrict__ A, long lda,
                     const bf16* __restrict__ B, long ldb,
                     int ksteps, bf16* As, bf16* Bs, f32x4 acc[4][4]) {
  const int tid  = threadIdx.x;
  const int lane = tid & 63;
  const int w    = tid >> 6;            // wave 0..3
  const int lr   = lane & 15;           // row/col within 16
  const int lk   = (lane >> 4) * 8;     // k-offset within 32
  const int wr   = (w >> 1) * 64;
  const int wc   = (w & 1) * 64;

  for (int kt = 0; kt < ksteps; ++kt) {
    bf16x8 av[4], bv[4];
#pragma unroll
    for (int c = 0; c < 4; ++c) {
      const int idx = c * 256 + tid;          // vec8 index 0..1023
      const int row = idx >> 3, col = (idx & 7) * 8;
      av[c] = *(const bf16x8*)(A + (long)row * lda + (long)kt * 64 + col);
      bv[c] = *(const bf16x8*)(B + (long)row * ldb + (long)kt * 64 + col);
    }
#pragma unroll
    for (int c = 0; c < 4; ++c) {
      const int idx = c * 256 + tid;
      const int row = idx >> 3, col = (idx & 7) * 8;
      *(bf16x8*)(As + row * 64 + col) = av[c];
      *(bf16x8*)(Bs + row * 64 + col) = bv[c];
    }
    __syncthreads();
#pragma unroll
    for (int kk = 0; kk < 2; ++kk) {
      bf16x8 af[4], bfr[4];
#pragma unroll
      for (int i = 0; i < 4; ++i)
        af[i] = *(const bf16x8*)(As + (wr + i * 16 + lr) * 64 + kk * 32 + lk);
#pragma unroll
      for (int i = 0; i < 4; ++i)
        bfr[i] = *(const bf16x8*)(Bs + (wc + i * 16 + lr) * 64 + kk * 32 + lk);
#pragma unroll
      for (int i = 0; i < 4; ++i)
#pragma unroll
        for (int j = 0; j < 4; ++j)
          acc[i][j] = __builtin_amdgcn_mfma_f32_16x16x32_bf16(af[i], bfr[j], acc[i][j], 0, 0, 0);
    }
    __syncthreads();
  }
}

// ---------------- GroupNorm stats: one block per (b,g) ----------------
__global__ __launch_bounds__(256) void k_gnstats(const float* __restrict__ x,
                                                 float2* __restrict__ stats) {
  const int bg = blockIdx.x, b = bg >> 5, g = bg & 31;
  const float* base = x + (size_t)b * 4096 * 512 + g * 16;
  const int tid = threadIdx.x;
  float s = 0.f, ss = 0.f;
  for (int it = 0; it < 64; ++it) {           // 16384 float4: 4096 px x 16 ch
    const int idx = it * 256 + tid;
    const int p = idx >> 2, c4 = (idx & 3) * 4;
    float4 v = *(const float4*)(base + (size_t)p * 512 + c4);
    s  += v.x + v.y + v.z + v.w;
    ss += v.x * v.x + v.y * v.y + v.z * v.z + v.w * v.w;
  }
  __shared__ float rs[256], rss[256];
  rs[tid] = s; rss[tid] = ss; __syncthreads();
  for (int off = 128; off; off >>= 1) {
    if (tid < off) { rs[tid] += rs[tid + off]; rss[tid] += rss[tid + off]; }
    __syncthreads();
  }
  if (tid == 0) {
    float mean = rs[0] * (1.f / 65536.f);
    float var  = rss[0] * (1.f / 65536.f) - mean * mean;
    stats[bg] = float2{mean, rsqrtf(var + 1e-5f)};
  }
}

// ---------------- GroupNorm apply: fp32 in -> bf16 out ----------------
__global__ __launch_bounds__(256) void k_gnapply(const float* __restrict__ x,
                                                 const float2* __restrict__ stats,
                                                 const float* __restrict__ gns,
                                                 const float* __restrict__ gnb,
                                                 bf16* __restrict__ h) {
  const int idx = blockIdx.x * 256 + threadIdx.x;   // 2,097,152 threads x 8 elems
  const int m = idx >> 6, c8 = (idx & 63) << 3;
  const int b = m >> 12, g = c8 >> 4;
  const float2 st = stats[(b << 5) | g];
  const float4 x0 = *(const float4*)(x + (size_t)m * 512 + c8);
  const float4 x1 = *(const float4*)(x + (size_t)m * 512 + c8 + 4);
  const float4 s0 = *(const float4*)(gns + c8);
  const float4 s1 = *(const float4*)(gns + c8 + 4);
  const float4 b0 = *(const float4*)(gnb + c8);
  const float4 b1 = *(const float4*)(gnb + c8 + 4);
  bf16x8 o;
  o[0] = (bf16)((x0.x - st.x) * st.y * s0.x + b0.x);
  o[1] = (bf16)((x0.y - st.x) * st.y * s0.y + b0.y);
  o[2] = (bf16)((x0.z - st.x) * st.y * s0.z + b0.z);
  o[3] = (bf16)((x0.w - st.x) * st.y * s0.w + b0.w);
  o[4] = (bf16)((x1.x - st.x) * st.y * s1.x + b1.x);
  o[5] = (bf16)((x1.y - st.x) * st.y * s1.y + b1.y);
  o[6] = (bf16)((x1.z - st.x) * st.y * s1.z + b1.z);
  o[7] = (bf16)((x1.w - st.x) * st.y * s1.w + b1.w);
  *(bf16x8*)(h + (size_t)m * 512 + c8) = o;
}

// ---------------- weight transpose+cast: WT[z*512 + n][k] = bf16(w_z[k][n]) ----------------
__global__ void k_wt(const float* __restrict__ wq, const float* __restrict__ wk,
                     const float* __restrict__ wv, const float* __restrict__ wp,
                     bf16* __restrict__ WT) {
  __shared__ float t[32][33];
  const int z = blockIdx.z;
  const float* src = (z == 0) ? wq : (z == 1) ? wk : (z == 2) ? wv : wp;
  const int n0 = blockIdx.x * 32, k0 = blockIdx.y * 32;
  const int tx = threadIdx.x, ty = threadIdx.y;   // (32, 8)
#pragma unroll
  for (int j = 0; j < 4; ++j)
    t[ty + j * 8][tx] = src[(size_t)(k0 + ty + j * 8) * 512 + n0 + tx];
  __syncthreads();
#pragma unroll
  for (int j = 0; j < 4; ++j)
    WT[(size_t)(z * 512 + n0 + ty + j * 8) * 512 + k0 + tx] = (bf16)t[tx][ty + j * 8];
}

// ---------------- GEMM: q,k = h_gn x WT(q,k); stored transposed [b][c][s] ----------------
__global__ __launch_bounds__(256) void k_gemm_qk(const bf16* __restrict__ hgn,
                                                 const bf16* __restrict__ WT,
                                                 const float* __restrict__ bq,
                                                 const float* __restrict__ bk,
                                                 bf16* __restrict__ qT,
                                                 bf16* __restrict__ kT) {
  __shared__ bf16 As[128 * 64], Bs[128 * 64];
  const int m0 = blockIdx.y * 128, n0 = blockIdx.x * 128;
  f32x4 acc[4][4]; zero_acc(acc);
  gemm128_core(hgn + (size_t)m0 * 512, 512, WT + (size_t)n0 * 512, 512, 8, As, Bs, acc);

  const int lane = threadIdx.x & 63, w = threadIdx.x >> 6;
  const int wr = (w >> 1) * 64, wc = (w & 1) * 64;
  const int rr = (lane >> 4) * 4, cc = lane & 15;
  const int region = n0 >> 9;                 // 0=q 1=k
  const float* bias = (region == 0) ? bq : bk;
  bf16* dst = (region == 0) ? qT : kT;
#pragma unroll
  for (int i = 0; i < 4; ++i) {
#pragma unroll
    for (int j = 0; j < 4; ++j) {
      const int gm = m0 + wr + i * 16 + rr;       // pixel rows gm..gm+3 (gm%4==0)
      const int gn = (n0 + wc + j * 16 + cc) & 511;
      const float bb = bias[gn];
      const int bidx = gm >> 12, s = gm & 4095;
      bf16x4 pk;
      pk[0] = (bf16)(acc[i][j][0] + bb); pk[1] = (bf16)(acc[i][j][1] + bb);
      pk[2] = (bf16)(acc[i][j][2] + bb); pk[3] = (bf16)(acc[i][j][3] + bb);
      *(bf16x4*)(dst + ((size_t)bidx * 512 + gn) * 4096 + s) = pk;
    }
  }
}

// ---------------- GEMM: v = h_gn x WT(v) + bv; normal layout [m][c] ----------------
__global__ __launch_bounds__(256) void k_gemm_v(const bf16* __restrict__ hgn,
                                                const bf16* __restrict__ WTv,
                                                const float* __restrict__ bv,
                                                bf16* __restrict__ vb) {
  __shared__ bf16 As[128 * 64], Bs[128 * 64];
  const int m0 = blockIdx.y * 128, n0 = blockIdx.x * 128;
  f32x4 acc[4][4]; zero_acc(acc);
  gemm128_core(hgn + (size_t)m0 * 512, 512, WTv + (size_t)n0 * 512, 512, 8, As, Bs, acc);

  const int lane = threadIdx.x & 63, w = threadIdx.x >> 6;
  const int wr = (w >> 1) * 64, wc = (w & 1) * 64;
  const int rr = (lane >> 4) * 4, cc = lane & 15;
#pragma unroll
  for (int i = 0; i < 4; ++i) {
#pragma unroll
    for (int j = 0; j < 4; ++j) {
      const int gm = m0 + wr + i * 16 + rr;
      const int gn = n0 + wc + j * 16 + cc;
      const float bb = bv[gn];
      bf16* p = vb + (size_t)gm * 512 + gn;
      p[0]    = (bf16)(acc[i][j][0] + bb);
      p[512]  = (bf16)(acc[i][j][1] + bb);
      p[1024] = (bf16)(acc[i][j][2] + bb);
      p[1536] = (bf16)(acc[i][j][3] + bb);
    }
  }
}

// ---------------- GEMM: attn partials = q^T k per batch, split-K=2 ----------------
__global__ __launch_bounds__(256) void k_gemm_attn(const bf16* __restrict__ qT,
                                                   const bf16* __restrict__ kT,
                                                   float* __restrict__ part) {
  __shared__ bf16 As[128 * 64], Bs[128 * 64];
  const int b = blockIdx.z >> 1, sp = blockIdx.z & 1;
  const int m0 = blockIdx.y * 128, n0 = blockIdx.x * 128;
  f32x4 acc[4][4]; zero_acc(acc);
  const bf16* A = qT + ((size_t)b * 512 + m0) * 4096 + sp * 2048;
  const bf16* B = kT + ((size_t)b * 512 + n0) * 4096 + sp * 2048;
  gemm128_core(A, 4096, B, 4096, 32, As, Bs, acc);

  const int lane = threadIdx.x & 63, w = threadIdx.x >> 6;
  const int wr = (w >> 1) * 64, wc = (w & 1) * 64;
  const int rr = (lane >> 4) * 4, cc = lane & 15;
  float* dst = part + (size_t)(sp * 8 + b) * 512 * 512;
#pragma unroll
  for (int i = 0; i < 4; ++i) {
#pragma unroll
    for (int j = 0; j < 4; ++j) {
      const int gm = m0 + wr + i * 16 + rr;
      const int gn = n0 + wc + j * 16 + cc;
      float* p = dst + (size_t)gm * 512 + gn;
      p[0]    = acc[i][j][0];
      p[512]  = acc[i][j][1];
      p[1024] = acc[i][j][2];
      p[1536] = acc[i][j][3];
    }
  }
}

// ---------------- softmax rows (reduce 2 split-K partials) ----------------
__global__ __launch_bounds__(128) void k_softmax(const float* __restrict__ part,
                                                 bf16* __restrict__ attn) {
  const int row = blockIdx.x, tid = threadIdx.x;   // row = b*512 + i
  const float* p0 = part + (size_t)row * 512 + tid * 4;
  const float* p1 = p0 + (size_t)8 * 512 * 512;
  const float4 a = *(const float4*)p0, c = *(const float4*)p1;
  const float v0 = a.x + c.x, v1 = a.y + c.y, v2 = a.z + c.z, v3 = a.w + c.w;
  __shared__ float red[128];
  red[tid] = fmaxf(fmaxf(v0, v1), fmaxf(v2, v3));
  __syncthreads();
  for (int off = 64; off; off >>= 1) {
    if (tid < off) red[tid] = fmaxf(red[tid], red[tid + off]);
    __syncthreads();
  }
  const float M = red[0];
  __syncthreads();
  const float e0 = __expf(v0 - M), e1 = __expf(v1 - M);
  const float e2 = __expf(v2 - M), e3 = __expf(v3 - M);
  red[tid] = e0 + e1 + e2 + e3;
  __syncthreads();
  for (int off = 64; off; off >>= 1) {
    if (tid < off) red[tid] += red[tid + off];
    __syncthreads();
  }
  const float inv = 1.f / red[0];
  bf16x4 o;
  o[0] = (bf16)(e0 * inv); o[1] = (bf16)(e1 * inv);
  o[2] = (bf16)(e2 * inv); o[3] = (bf16)(e3 * inv);
  *(bf16x4*)(attn + (size_t)row * 512 + tid * 4) = o;
}

// ---------------- GEMM: h2 = v x attn^T per batch ----------------
__global__ __launch_bounds__(256) void k_gemm_pv(const bf16* __restrict__ vb,
                                                 const bf16* __restrict__ attn,
                                                 bf16* __restrict__ h2) {
  __shared__ bf16 As[128 * 64], Bs[128 * 64];
  const int b = blockIdx.z;
  const int m0 = blockIdx.y * 128, n0 = blockIdx.x * 128;
  f32x4 acc[4][4]; zero_acc(acc);
  gemm128_core(vb + ((size_t)b * 4096 + m0) * 512, 512,
               attn + ((size_t)b * 512 + n0) * 512, 512, 8, As, Bs, acc);

  const int lane = threadIdx.x & 63, w = threadIdx.x >> 6;
  const int wr = (w >> 1) * 64, wc = (w & 1) * 64;
  const int rr = (lane >> 4) * 4, cc = lane & 15;
  bf16* dst = h2 + (size_t)b * 4096 * 512;
#pragma unroll
  for (int i = 0; i < 4; ++i) {
#pragma unroll
    for (int j = 0; j < 4; ++j) {
      const int gm = m0 + wr + i * 16 + rr;
      const int gn = n0 + wc + j * 16 + cc;
      bf16* p = dst + (size_t)gm * 512 + gn;
      p[0]    = (bf16)acc[i][j][0];
      p[512]  = (bf16)acc[i][j][1];
      p[1024] = (bf16)acc[i][j][2];
      p[1536] = (bf16)acc[i][j][3];
    }
  }
}

// ---------------- GEMM: out = fp32(x + h2 x wpT + bp) ----------------
__global__ __launch_bounds__(256) void k_gemm_proj(const bf16* __restrict__ h2,
                                                   const bf16* __restrict__ wpT,
                                                   const float* __restrict__ bp,
                                                   const float* __restrict__ x,
                                                   float* __restrict__ out) {
  __shared__ bf16 As[128 * 64], Bs[128 * 64];
  const int m0 = blockIdx.y * 128, n0 = blockIdx.x * 128;
  f32x4 acc[4][4]; zero_acc(acc);
  gemm128_core(h2 + (size_t)m0 * 512, 512, wpT + (size_t)n0 * 512, 512, 8, As, Bs, acc);

  const int lane = threadIdx.x & 63, w = threadIdx.x >> 6;
  const int wr = (w >> 1) * 64, wc = (w & 1) * 64;
  const int rr = (lane >> 4) * 4, cc = lane & 15;
#pragma unroll
  for (int i = 0; i < 4; ++i) {
#pragma unroll
    for (int j = 0; j < 4; ++j) {
      const int gm = m0 + wr + i * 16 + rr;
      const int gn = n0 + wc + j * 16 + cc;
      const float bb = bp[gn];
#pragma unroll
      for (int jj = 0; jj < 4; ++jj) {
        const size_t off = (size_t)(gm + jj) * 512 + gn;
        out[off] = acc[i][j][jj] + bb + x[off];
      }
    }
  }
}

extern "C" void kernel_launch(void* const* d_in, const int* in_sizes, int n_in,
                              void* d_out, int out_size, void* d_ws, size_t ws_size,
                              hipStream_t stream) {
  const float* x   = (const float*)d_in[0];
  const float* wq  = (const float*)d_in[1];
  const float* bq  = (const float*)d_in[2];
  const float* wk  = (const float*)d_in[3];
  const float* bk  = (const float*)d_in[4];
  const float* wv  = (const float*)d_in[5];
  const float* bv  = (const float*)d_in[6];
  const float* wp  = (const float*)d_in[7];
  const float* bp  = (const float*)d_in[8];
  const float* gns = (const float*)d_in[9];
  const float* gnb = (const float*)d_in[10];
  float* out = (float*)d_out;

  const size_t MB = 1ull << 20;
  char* wsb = (char*)d_ws;
  bf16*   WT    = (bf16*)(wsb);             // [2048][512] bf16, 2 MB
  float2* stats = (float2*)(wsb + 2 * MB);  // [256]
  bf16*   h_gn  = (bf16*)(wsb + 3 * MB);    // [32768][512] bf16, 32 MB
  bf16*   h2    = (bf16*)(wsb + 3 * MB);    // overlay (h_gn dead after v GEMM)
  bf16*   qT    = (bf16*)(wsb + 35 * MB);   // [8][512][4096] bf16, 32 MB
  bf16*   attn  = (bf16*)(wsb + 35 * MB);   // overlay (qT dead after attn GEMM)
  bf16*   kT    = (bf16*)(wsb + 67 * MB);   // [8][512][4096] bf16, 32 MB
  bf16*   vb    = (bf16*)(wsb + 67 * MB);   // overlay (kT dead after attn GEMM)
  float*  part  = (float*)(wsb + 99 * MB);  // [2][8][512][512] f32, 16 MB

  k_wt       <<<dim3(16, 16, 4), dim3(32, 8), 0, stream>>>(wq, wk, wv, wp, WT);
  k_gnstats  <<<dim3(256),       dim3(256),   0, stream>>>(x, stats);
  k_gnapply  <<<dim3(8192),      dim3(256),   0, stream>>>(x, stats, gns, gnb, h_gn);
  k_gemm_qk  <<<dim3(8, 256),    dim3(256),   0, stream>>>(h_gn, WT, bq, bk, qT, kT);
  k_gemm_attn<<<dim3(4, 4, 16),  dim3(256),   0, stream>>>(qT, kT, part);
  k_softmax  <<<dim3(4096),      dim3(128),   0, stream>>>(part, attn);
  k_gemm_v   <<<dim3(4, 256),    dim3(256),   0, stream>>>(h_gn, WT + (size_t)1024 * 512, bv, vb);
  k_gemm_pv  <<<dim3(4, 32, 8),  dim3(256),   0, stream>>>(vb, attn, h2);
  k_gemm_proj<<<dim3(4, 256),    dim3(256),   0, stream>>>(h2, WT + (size_t)1536 * 512, bp, x, out);
}

// Round 5
// 226.439 us; speedup vs baseline: 1.2290x; 1.2290x over previous
//
#include <hip/hip_runtime.h>
#include <hip/hip_bf16.h>

// SelfAttention (channel attention) on MI355X. Inputs fp32, OUTPUT fp32.
// Algebraic form (C=512 << HW=4096):
//   Hn = GN(x) (bf16)                         G_b = Hn_b^T Hn_b   (Gram, per batch)
//   L_b = Wq^T G_b Wk + (Wq^T s_b) bk^T + bq (s_b^T Wk) + 4096 bq bk^T
//   attn_b = softmax_rows(L_b)
//   C_b^T = Wp^T attn_b Wv^T ;  d_b = Wp^T attn_b bv
//   out = x + Hn C_b + d_b + bp
// gemm(A,B) convention: C[m][n] = sum_k A[m][k]*B[n][k] = A B^T (both K-contiguous).
// Workspace (115 MB):
//   [0,2)MB   WT   [2048][512] bf16 (Wq,Wk,Wv,Wp transposed)
//   [2,2.5)   wvb  [512][512] bf16 (Wv original layout)
//   2.5MB     stats [256] float2 ; +64K s[8][512]f32 ; +128K uq ; +192K vkv ; +256K dv
//   [3,35)    Hn   [8*4096][512] bf16
//   [35,67)   HnT  [8][512][4096] bf16
//   [67,83)   Gpart[2][8][512][512] f32 (gram split-K partials)
//   [83,87)   G    [8][512][512] bf16
//   [87,91)   M1   [8][512][512] bf16 (= Wq^T G)
//   [91,99)   L    [8][512][512] f32
//   [99,103)  attn [8][512][512] bf16
//   [103,107) attnT
//   [107,111) T    (= Wp^T attn)
//   [111,115) CT   (= C^T = Wp^T attn Wv^T)

using bf16   = __bf16;
using bf16x8 = __attribute__((ext_vector_type(8))) __bf16;
using bf16x4 = __attribute__((ext_vector_type(4))) __bf16;
using f32x4  = __attribute__((ext_vector_type(4))) float;

#define DI __device__ __forceinline__

// ---------------- 128x128 tile core (4 waves, 64x64 quadrant each) ----------------
DI void gemm128_core(const bf16* __restrict__ A, long lda,
                     const bf16* __restrict__ B, long ldb,
                     int ksteps, bf16* As, bf16* Bs, f32x4 acc[4][4]) {
  const int tid  = threadIdx.x;
  const int lane = tid & 63;
  const int w    = tid >> 6;
  const int lr   = lane & 15;
  const int lk   = (lane >> 4) * 8;
  const int wr   = (w >> 1) * 64;
  const int wc   = (w & 1) * 64;

  for (int kt = 0; kt < ksteps; ++kt) {
    bf16x8 av[4], bv[4];
#pragma unroll
    for (int c = 0; c < 4; ++c) {
      const int idx = c * 256 + tid;
      const int row = idx >> 3, col = (idx & 7) * 8;
      av[c] = *(const bf16x8*)(A + (long)row * lda + (long)kt * 64 + col);
      bv[c] = *(const bf16x8*)(B + (long)row * ldb + (long)kt * 64 + col);
    }
#pragma unroll
    for (int c = 0; c < 4; ++c) {
      const int idx = c * 256 + tid;
      const int row = idx >> 3, col = (idx & 7) * 8;
      *(bf16x8*)(As + row * 64 + col) = av[c];
      *(bf16x8*)(Bs + row * 64 + col) = bv[c];
    }
    __syncthreads();
#pragma unroll
    for (int kk = 0; kk < 2; ++kk) {
      bf16x8 af[4], bfr[4];
#pragma unroll
      for (int i = 0; i < 4; ++i)
        af[i] = *(const bf16x8*)(As + (wr + i * 16 + lr) * 64 + kk * 32 + lk);
#pragma unroll
      for (int i = 0; i < 4; ++i)
        bfr[i] = *(const bf16x8*)(Bs + (wc + i * 16 + lr) * 64 + kk * 32 + lk);
#pragma unroll
      for (int i = 0; i < 4; ++i)
#pragma unroll
        for (int j = 0; j < 4; ++j)
          acc[i][j] = __builtin_amdgcn_mfma_f32_16x16x32_bf16(af[i], bfr[j], acc[i][j], 0, 0, 0);
    }
    __syncthreads();
  }
}

// ---------------- 64x64 tile core (4 waves, 32x32 quadrant each) ----------------
DI void gemm64_core(const bf16* __restrict__ A, long lda,
                    const bf16* __restrict__ B, long ldb,
                    int ksteps, bf16* As, bf16* Bs, f32x4 acc[2][2]) {
  const int tid  = threadIdx.x;
  const int lane = tid & 63;
  const int w    = tid >> 6;
  const int lr   = lane & 15;
  const int lk   = (lane >> 4) * 8;
  const int wr   = (w >> 1) * 32;
  const int wc   = (w & 1) * 32;

  for (int kt = 0; kt < ksteps; ++kt) {
    bf16x8 av[2], bv[2];
#pragma unroll
    for (int c = 0; c < 2; ++c) {
      const int idx = c * 256 + tid;            // 512 vec8 per matrix
      const int row = idx >> 3, col = (idx & 7) * 8;
      av[c] = *(const bf16x8*)(A + (long)row * lda + (long)kt * 64 + col);
      bv[c] = *(const bf16x8*)(B + (long)row * ldb + (long)kt * 64 + col);
    }
#pragma unroll
    for (int c = 0; c < 2; ++c) {
      const int idx = c * 256 + tid;
      const int row = idx >> 3, col = (idx & 7) * 8;
      *(bf16x8*)(As + row * 64 + col) = av[c];
      *(bf16x8*)(Bs + row * 64 + col) = bv[c];
    }
    __syncthreads();
#pragma unroll
    for (int kk = 0; kk < 2; ++kk) {
      bf16x8 af[2], bfr[2];
#pragma unroll
      for (int i = 0; i < 2; ++i)
        af[i] = *(const bf16x8*)(As + (wr + i * 16 + lr) * 64 + kk * 32 + lk);
#pragma unroll
      for (int i = 0; i < 2; ++i)
        bfr[i] = *(const bf16x8*)(Bs + (wc + i * 16 + lr) * 64 + kk * 32 + lk);
#pragma unroll
      for (int i = 0; i < 2; ++i)
#pragma unroll
        for (int j = 0; j < 2; ++j)
          acc[i][j] = __builtin_amdgcn_mfma_f32_16x16x32_bf16(af[i], bfr[j], acc[i][j], 0, 0, 0);
    }
    __syncthreads();
  }
}

// ---------------- GroupNorm stats: one block per (b,g) ----------------
__global__ __launch_bounds__(256) void k_gnstats(const float* __restrict__ x,
                                                 float2* __restrict__ stats) {
  const int bg = blockIdx.x, b = bg >> 5, g = bg & 31;
  const float* base = x + (size_t)b * 4096 * 512 + g * 16;
  const int tid = threadIdx.x;
  float s = 0.f, ss = 0.f;
  for (int it = 0; it < 64; ++it) {
    const int idx = it * 256 + tid;
    const int p = idx >> 2, c4 = (idx & 3) * 4;
    float4 v = *(const float4*)(base + (size_t)p * 512 + c4);
    s  += v.x + v.y + v.z + v.w;
    ss += v.x * v.x + v.y * v.y + v.z * v.z + v.w * v.w;
  }
  __shared__ float rs[256], rss[256];
  rs[tid] = s; rss[tid] = ss; __syncthreads();
  for (int off = 128; off; off >>= 1) {
    if (tid < off) { rs[tid] += rs[tid + off]; rss[tid] += rss[tid + off]; }
    __syncthreads();
  }
  if (tid == 0) {
    float mean = rs[0] * (1.f / 65536.f);
    float var  = rss[0] * (1.f / 65536.f) - mean * mean;
    stats[bg] = float2{mean, rsqrtf(var + 1e-5f)};
  }
}

// ---------------- GN apply -> Hn (normal) + HnT (transposed) + col-sums s ----------------
__global__ __launch_bounds__(256) void k_gnapply_t(const float* __restrict__ x,
                                                   const float2* __restrict__ stats,
                                                   const float* __restrict__ gns,
                                                   const float* __restrict__ gnb,
                                                   bf16* __restrict__ Hn,
                                                   bf16* __restrict__ HnT,
                                                   float* __restrict__ s) {
  __shared__ bf16 tile[64 * 516];   // 64 px x 512 ch, padded stride (8B-aligned rows)
  __shared__ float cs[512];
  const int tid = threadIdx.x;
  const int blk = blockIdx.x;       // 0..511
  const int b = blk >> 6, p0 = (blk & 63) * 64;
  cs[tid] = 0.f; cs[tid + 256] = 0.f;
  __syncthreads();

  const int c4 = (tid & 127) * 4;   // fixed channel quad per thread
  const int hi = tid >> 7;          // 0/1: even/odd px
  const float2 st = stats[b * 32 + (c4 >> 4)];
  const float4 sc = *(const float4*)(gns + c4);
  const float4 bi = *(const float4*)(gnb + c4);
  float a0 = 0.f, a1 = 0.f, a2 = 0.f, a3 = 0.f;
  for (int i = 0; i < 32; ++i) {
    const int px = i * 2 + hi;
    const float4 xv = *(const float4*)(x + ((size_t)(b * 4096 + p0 + px)) * 512 + c4);
    const float h0 = (xv.x - st.x) * st.y * sc.x + bi.x;
    const float h1 = (xv.y - st.x) * st.y * sc.y + bi.y;
    const float h2 = (xv.z - st.x) * st.y * sc.z + bi.z;
    const float h3 = (xv.w - st.x) * st.y * sc.w + bi.w;
    a0 += h0; a1 += h1; a2 += h2; a3 += h3;
    bf16x4 hv;
    hv[0] = (bf16)h0; hv[1] = (bf16)h1; hv[2] = (bf16)h2; hv[3] = (bf16)h3;
    *(bf16x4*)(Hn + ((size_t)(b * 4096 + p0 + px)) * 512 + c4) = hv;
    *(bf16x4*)(tile + px * 516 + c4) = hv;
  }
  atomicAdd(&cs[c4 + 0], a0); atomicAdd(&cs[c4 + 1], a1);
  atomicAdd(&cs[c4 + 2], a2); atomicAdd(&cs[c4 + 3], a3);
  __syncthreads();
  atomicAdd(s + b * 512 + tid, cs[tid]);
  atomicAdd(s + b * 512 + 256 + tid, cs[tid + 256]);

  // transposed write: HnT[b][c][p0..p0+63]
  for (int cg = 0; cg < 16; ++cg) {
    const int c  = cg * 32 + (tid >> 3);
    const int so = (tid & 7) * 8;
    bf16x8 pk;
#pragma unroll
    for (int k = 0; k < 8; ++k) pk[k] = tile[(so + k) * 516 + c];
    *(bf16x8*)(HnT + ((size_t)(b * 512 + c)) * 4096 + p0 + so) = pk;
  }
}

// ---------------- weight transpose+cast; also Wv original-layout bf16 copy ----------------
__global__ void k_wt(const float* __restrict__ wq, const float* __restrict__ wk,
                     const float* __restrict__ wv, const float* __restrict__ wp,
                     bf16* __restrict__ WT, bf16* __restrict__ wvb) {
  __shared__ float t[32][33];
  const int z = blockIdx.z;
  const float* src = (z == 0) ? wq : (z == 1) ? wk : (z == 2) ? wv : wp;
  const int n0 = blockIdx.x * 32, k0 = blockIdx.y * 32;
  const int tx = threadIdx.x, ty = threadIdx.y;   // (32, 8)
#pragma unroll
  for (int j = 0; j < 4; ++j) {
    const float v = src[(size_t)(k0 + ty + j * 8) * 512 + n0 + tx];
    t[ty + j * 8][tx] = v;
    if (z == 2) wvb[(size_t)(k0 + ty + j * 8) * 512 + n0 + tx] = (bf16)v;
  }
  __syncthreads();
#pragma unroll
  for (int j = 0; j < 4; ++j)
    WT[(size_t)(z * 512 + n0 + ty + j * 8) * 512 + k0 + tx] = (bf16)t[tx][ty + j * 8];
}

// ---------------- zero s ----------------
__global__ void k_zero(float* __restrict__ s) {
  s[blockIdx.x * 256 + threadIdx.x] = 0.f;
}

// ---------------- Gram partials: G_b = HnT_b HnT_b^T, split-K=2 ----------------
__global__ __launch_bounds__(256) void k_gram(const bf16* __restrict__ HnT,
                                              float* __restrict__ part) {
  __shared__ bf16 As[128 * 64], Bs[128 * 64];
  const int b = blockIdx.z >> 1, sp = blockIdx.z & 1;
  const int m0 = blockIdx.y * 128, n0 = blockIdx.x * 128;
  f32x4 acc[4][4];
#pragma unroll
  for (int i = 0; i < 4; ++i)
#pragma unroll
    for (int j = 0; j < 4; ++j) acc[i][j] = (f32x4){0.f, 0.f, 0.f, 0.f};
  const bf16* A = HnT + ((size_t)b * 512 + m0) * 4096 + sp * 2048;
  const bf16* B = HnT + ((size_t)b * 512 + n0) * 4096 + sp * 2048;
  gemm128_core(A, 4096, B, 4096, 32, As, Bs, acc);

  const int lane = threadIdx.x & 63, w = threadIdx.x >> 6;
  const int wr = (w >> 1) * 64, wc = (w & 1) * 64;
  const int rr = (lane >> 4) * 4, cc = lane & 15;
  float* dst = part + (size_t)(sp * 8 + b) * 512 * 512;
#pragma unroll
  for (int i = 0; i < 4; ++i) {
#pragma unroll
    for (int j = 0; j < 4; ++j) {
      const int gm = m0 + wr + i * 16 + rr;
      const int gn = n0 + wc + j * 16 + cc;
      float* p = dst + (size_t)gm * 512 + gn;
      p[0]    = acc[i][j][0];
      p[512]  = acc[i][j][1];
      p[1024] = acc[i][j][2];
      p[1536] = acc[i][j][3];
    }
  }
}

// ---------------- reduce gram partials -> bf16 G ----------------
__global__ __launch_bounds__(256) void k_gsum(const float* __restrict__ part,
                                              bf16* __restrict__ G) {
  const size_t i4 = ((size_t)blockIdx.x * 256 + threadIdx.x) * 4;
  const float4 a = *(const float4*)(part + i4);
  const float4 c = *(const float4*)(part + i4 + (size_t)8 * 512 * 512);
  bf16x4 o;
  o[0] = (bf16)(a.x + c.x); o[1] = (bf16)(a.y + c.y);
  o[2] = (bf16)(a.z + c.z); o[3] = (bf16)(a.w + c.w);
  *(bf16x4*)(G + i4) = o;
}

// ---------------- small vectors: uq=Wq^T s, vkv=Wk^T s (mode 0); dv=T bv (mode 1) ----------------
__global__ __launch_bounds__(512) void k_vecs(const bf16* __restrict__ WT,
                                              const float* __restrict__ s,
                                              const float* __restrict__ bv,
                                              const bf16* __restrict__ T,
                                              float* __restrict__ uq,
                                              float* __restrict__ vkv,
                                              float* __restrict__ dv,
                                              int mode) {
  const int i = threadIdx.x;
  if (mode == 0) {
    const int z = blockIdx.x;                 // 0..15
    const int which = z >> 3, b = z & 7;
    const bf16* row = WT + ((size_t)(which * 512 + i)) * 512;
    const float* sv = s + b * 512;
    float acc = 0.f;
    for (int c = 0; c < 512; ++c) acc += (float)row[c] * sv[c];
    (which == 0 ? uq : vkv)[b * 512 + i] = acc;
  } else {
    const int b = blockIdx.x;
    const bf16* row = T + (size_t)b * 262144 + (size_t)i * 512;
    float acc = 0.f;
    for (int c = 0; c < 512; ++c) acc += (float)row[c] * bv[c];
    dv[b * 512 + i] = acc;
  }
}

// ---------------- batched small GEMM 512x512x512, bf16 out ----------------
__global__ __launch_bounds__(256) void k_sg64_bf(const bf16* __restrict__ Ab, long a_bs,
                                                 const bf16* __restrict__ Bb, long b_bs,
                                                 bf16* __restrict__ Cb) {
  __shared__ bf16 As[64 * 64], Bs[64 * 64];
  const int b = blockIdx.z;
  const int m0 = blockIdx.y * 64, n0 = blockIdx.x * 64;
  f32x4 acc[2][2];
#pragma unroll
  for (int i = 0; i < 2; ++i)
#pragma unroll
    for (int j = 0; j < 2; ++j) acc[i][j] = (f32x4){0.f, 0.f, 0.f, 0.f};
  gemm64_core(Ab + (size_t)b * a_bs + (size_t)m0 * 512, 512,
              Bb + (size_t)b * b_bs + (size_t)n0 * 512, 512, 8, As, Bs, acc);

  const int lane = threadIdx.x & 63, w = threadIdx.x >> 6;
  const int wr = (w >> 1) * 32, wc = (w & 1) * 32;
  const int rr = (lane >> 4) * 4, cc = lane & 15;
  bf16* dst = Cb + (size_t)b * 262144;
#pragma unroll
  for (int i = 0; i < 2; ++i) {
#pragma unroll
    for (int j = 0; j < 2; ++j) {
      const int gm = m0 + wr + i * 16 + rr;
      const int gn = n0 + wc + j * 16 + cc;
      bf16* p = dst + (size_t)gm * 512 + gn;
      p[0]    = (bf16)acc[i][j][0];
      p[512]  = (bf16)acc[i][j][1];
      p[1024] = (bf16)acc[i][j][2];
      p[1536] = (bf16)acc[i][j][3];
    }
  }
}

// ---------------- batched small GEMM 512x512x512, fp32 out ----------------
__global__ __launch_bounds__(256) void k_sg64_f32(const bf16* __restrict__ Ab, long a_bs,
                                                  const bf16* __restrict__ Bb, long b_bs,
                                                  float* __restrict__ Cb) {
  __shared__ bf16 As[64 * 64], Bs[64 * 64];
  const int b = blockIdx.z;
  const int m0 = blockIdx.y * 64, n0 = blockIdx.x * 64;
  f32x4 acc[2][2];
#pragma unroll
  for (int i = 0; i < 2; ++i)
#pragma unroll
    for (int j = 0; j < 2; ++j) acc[i][j] = (f32x4){0.f, 0.f, 0.f, 0.f};
  gemm64_core(Ab + (size_t)b * a_bs + (size_t)m0 * 512, 512,
              Bb + (size_t)b * b_bs + (size_t)n0 * 512, 512, 8, As, Bs, acc);

  const int lane = threadIdx.x & 63, w = threadIdx.x >> 6;
  const int wr = (w >> 1) * 32, wc = (w & 1) * 32;
  const int rr = (lane >> 4) * 4, cc = lane & 15;
  float* dst = Cb + (size_t)b * 262144;
#pragma unroll
  for (int i = 0; i < 2; ++i) {
#pragma unroll
    for (int j = 0; j < 2; ++j) {
      const int gm = m0 + wr + i * 16 + rr;
      const int gn = n0 + wc + j * 16 + cc;
      float* p = dst + (size_t)gm * 512 + gn;
      p[0]    = acc[i][j][0];
      p[512]  = acc[i][j][1];
      p[1024] = acc[i][j][2];
      p[1536] = acc[i][j][3];
    }
  }
}

// ---------------- softmax rows of L (+rank-1 bias terms) -> attn bf16 ----------------
__global__ __launch_bounds__(128) void k_softmax(const float* __restrict__ L,
                                                 const float* __restrict__ uq,
                                                 const float* __restrict__ vkv,
                                                 const float* __restrict__ bq,
                                                 const float* __restrict__ bk,
                                                 bf16* __restrict__ attn) {
  const int row = blockIdx.x, tid = threadIdx.x;   // row = b*512 + i
  const int b = row >> 9, i = row & 511;
  const float r  = uq[b * 512 + i];
  const float q0 = bq[i];
  const float4 l  = *(const float4*)(L + (size_t)row * 512 + tid * 4);
  const float4 bk4 = *(const float4*)(bk + tid * 4);
  const float4 vk4 = *(const float4*)(vkv + b * 512 + tid * 4);
  const float v0 = l.x + r * bk4.x + q0 * (vk4.x + 4096.f * bk4.x);
  const float v1 = l.y + r * bk4.y + q0 * (vk4.y + 4096.f * bk4.y);
  const float v2 = l.z + r * bk4.z + q0 * (vk4.z + 4096.f * bk4.z);
  const float v3 = l.w + r * bk4.w + q0 * (vk4.w + 4096.f * bk4.w);
  __shared__ float red[128];
  red[tid] = fmaxf(fmaxf(v0, v1), fmaxf(v2, v3));
  __syncthreads();
  for (int off = 64; off; off >>= 1) {
    if (tid < off) red[tid] = fmaxf(red[tid], red[tid + off]);
    __syncthreads();
  }
  const float M = red[0];
  __syncthreads();
  const float e0 = __expf(v0 - M), e1 = __expf(v1 - M);
  const float e2 = __expf(v2 - M), e3 = __expf(v3 - M);
  red[tid] = e0 + e1 + e2 + e3;
  __syncthreads();
  for (int off = 64; off; off >>= 1) {
    if (tid < off) red[tid] += red[tid + off];
    __syncthreads();
  }
  const float inv = 1.f / red[0];
  bf16x4 o;
  o[0] = (bf16)(e0 * inv); o[1] = (bf16)(e1 * inv);
  o[2] = (bf16)(e2 * inv); o[3] = (bf16)(e3 * inv);
  *(bf16x4*)(attn + (size_t)row * 512 + tid * 4) = o;
}

// ---------------- attn transpose per batch ----------------
__global__ void k_att_t(const bf16* __restrict__ attn, bf16* __restrict__ attnT) {
  __shared__ bf16 t[32][33];
  const int b = blockIdx.z;
  const int n0 = blockIdx.x * 32, k0 = blockIdx.y * 32;
  const int tx = threadIdx.x, ty = threadIdx.y;
#pragma unroll
  for (int j = 0; j < 4; ++j)
    t[ty + j * 8][tx] = attn[(size_t)b * 262144 + (size_t)(k0 + ty + j * 8) * 512 + n0 + tx];
  __syncthreads();
#pragma unroll
  for (int j = 0; j < 4; ++j)
    attnT[(size_t)b * 262144 + (size_t)(n0 + ty + j * 8) * 512 + k0 + tx] = t[tx][ty + j * 8];
}

// ---------------- final: out = x + Hn C_b + d_b + bp ----------------
__global__ __launch_bounds__(256) void k_final(const bf16* __restrict__ Hn,
                                               const bf16* __restrict__ CT,
                                               const float* __restrict__ dv,
                                               const float* __restrict__ bp,
                                               const float* __restrict__ x,
                                               float* __restrict__ out) {
  __shared__ bf16 As[128 * 64], Bs[128 * 64];
  const int b = blockIdx.z;
  const int m0 = blockIdx.y * 128, n0 = blockIdx.x * 128;
  f32x4 acc[4][4];
#pragma unroll
  for (int i = 0; i < 4; ++i)
#pragma unroll
    for (int j = 0; j < 4; ++j) acc[i][j] = (f32x4){0.f, 0.f, 0.f, 0.f};
  gemm128_core(Hn + ((size_t)b * 4096 + m0) * 512, 512,
               CT + (size_t)b * 262144 + (size_t)n0 * 512, 512, 8, As, Bs, acc);

  const int lane = threadIdx.x & 63, w = threadIdx.x >> 6;
  const int wr = (w >> 1) * 64, wc = (w & 1) * 64;
  const int rr = (lane >> 4) * 4, cc = lane & 15;
#pragma unroll
  for (int i = 0; i < 4; ++i) {
#pragma unroll
    for (int j = 0; j < 4; ++j) {
      const int gm = m0 + wr + i * 16 + rr;
      const int gn = n0 + wc + j * 16 + cc;
      const float add = dv[b * 512 + gn] + bp[gn];
#pragma unroll
      for (int jj = 0; jj < 4; ++jj) {
        const size_t off = ((size_t)(b * 4096 + gm + jj)) * 512 + gn;
        out[off] = acc[i][j][jj] + add + x[off];
      }
    }
  }
}

extern "C" void kernel_launch(void* const* d_in, const int* in_sizes, int n_in,
                              void* d_out, int out_size, void* d_ws, size_t ws_size,
                              hipStream_t stream) {
  const float* x   = (const float*)d_in[0];
  const float* wq  = (const float*)d_in[1];
  const float* bq  = (const float*)d_in[2];
  const float* wk  = (const float*)d_in[3];
  const float* bk  = (const float*)d_in[4];
  const float* wv  = (const float*)d_in[5];
  const float* bv  = (const float*)d_in[6];
  const float* wp  = (const float*)d_in[7];
  const float* bp  = (const float*)d_in[8];
  const float* gns = (const float*)d_in[9];
  const float* gnb = (const float*)d_in[10];
  float* out = (float*)d_out;

  const size_t MB = 1ull << 20;
  const size_t KB = 1024;
  char* wsb = (char*)d_ws;
  bf16*   WT    = (bf16*)(wsb);                       // 2 MB
  bf16*   wvb   = (bf16*)(wsb + 2 * MB);              // 512 KB
  float2* stats = (float2*)(wsb + 2 * MB + 512 * KB); // 2 KB
  float*  s     = (float*)(wsb + 2 * MB + 576 * KB);  // 16 KB
  float*  uq    = (float*)(wsb + 2 * MB + 640 * KB);  // 16 KB
  float*  vkv   = (float*)(wsb + 2 * MB + 704 * KB);  // 16 KB
  float*  dv    = (float*)(wsb + 2 * MB + 768 * KB);  // 16 KB
  bf16*   Hn    = (bf16*)(wsb + 3 * MB);              // 32 MB
  bf16*   HnT   = (bf16*)(wsb + 35 * MB);             // 32 MB
  float*  part  = (float*)(wsb + 67 * MB);            // 16 MB
  bf16*   G     = (bf16*)(wsb + 83 * MB);             // 4 MB
  bf16*   M1    = (bf16*)(wsb + 87 * MB);             // 4 MB
  float*  L     = (float*)(wsb + 91 * MB);            // 8 MB
  bf16*   attn  = (bf16*)(wsb + 99 * MB);             // 4 MB
  bf16*   attnT = (bf16*)(wsb + 103 * MB);            // 4 MB
  bf16*   T     = (bf16*)(wsb + 107 * MB);            // 4 MB
  bf16*   CT    = (bf16*)(wsb + 111 * MB);            // 4 MB

  const long S2 = 512 * 512;   // 262144

  k_wt        <<<dim3(16, 16, 4), dim3(32, 8), 0, stream>>>(wq, wk, wv, wp, WT, wvb);
  k_zero      <<<dim3(16),        dim3(256),   0, stream>>>(s);
  k_gnstats   <<<dim3(256),       dim3(256),   0, stream>>>(x, stats);
  k_gnapply_t <<<dim3(512),       dim3(256),   0, stream>>>(x, stats, gns, gnb, Hn, HnT, s);
  k_gram      <<<dim3(4, 4, 16),  dim3(256),   0, stream>>>(HnT, part);
  k_gsum      <<<dim3(2048),      dim3(256),   0, stream>>>(part, G);
  k_vecs      <<<dim3(16),        dim3(512),   0, stream>>>(WT, s, bv, T, uq, vkv, dv, 0);
  // M1 = Wq^T G   (A = WT_q shared, B = G batched)
  k_sg64_bf   <<<dim3(8, 8, 8),   dim3(256),   0, stream>>>(WT, 0, G, S2, M1);
  // L = M1 Wk     (A = M1 batched, B = WT_k shared -> contraction with Wk columns)
  k_sg64_f32  <<<dim3(8, 8, 8),   dim3(256),   0, stream>>>(M1, S2, WT + (size_t)512 * 512, 0, L);
  k_softmax   <<<dim3(4096),      dim3(128),   0, stream>>>(L, uq, vkv, bq, bk, attn);
  k_att_t     <<<dim3(16, 16, 8), dim3(32, 8), 0, stream>>>(attn, attnT);
  // T = Wp^T attn (A = WT_p shared, B = attnT batched)
  k_sg64_bf   <<<dim3(8, 8, 8),   dim3(256),   0, stream>>>(WT + (size_t)3 * 512 * 512, 0, attnT, S2, T);
  k_vecs      <<<dim3(8),         dim3(512),   0, stream>>>(WT, s, bv, T, uq, vkv, dv, 1);
  // CT = T Wv^T   (A = T batched, B = wvb shared)
  k_sg64_bf   <<<dim3(8, 8, 8),   dim3(256),   0, stream>>>(T, S2, wvb, 0, CT);
  k_final     <<<dim3(4, 32, 8),  dim3(256),   0, stream>>>(Hn, CT, dv, bp, x, out);
}

// Round 6
// 195.678 us; speedup vs baseline: 1.4222x; 1.1572x over previous
//
#include <hip/hip_runtime.h>
#include <hip/hip_bf16.h>

// SelfAttention (channel attention) on MI355X. Inputs fp32, OUTPUT fp32.
// Algebraic form (C=512 << HW=4096):
//   Hn = GN(x) (bf16)                         G_b = Hn_b^T Hn_b   (Gram, per batch)
//   L_b = Wq^T G_b Wk + (Wq^T s_b) bk^T + bq (s_b^T Wk) + 4096 bq bk^T
//   attn_b = softmax_rows(L_b)
//   C_b^T = Wp^T attn_b Wv^T ;  d_b = Wp^T attn_b bv
//   out = x + Hn C_b + d_b + bp
// gemm(A,B) convention: C[m][n] = sum_k A[m][k]*B[n][k] = A B^T (both K-contiguous).
// R6: gram = symmetric upper-tri tiles + split-K=4 + XCD-compact (xcd==batch);
//     LDS XOR-swizzle in GEMM cores; k_final XCD-compact grid.
// Workspace (115 MB):
//   [0,2)MB   WT [2048][512] bf16 ; [2,2.5) wvb ; 2.5MB stats/s/uq/vkv/dv
//   [3,35)    Hn   [8*4096][512] bf16
//   [35,67)   HnT  [8][512][4096] bf16
//   [67,99)   part [4][8][512][512] f32   -> later attn(67) attnT(71) T(75) CT(79)
//   [99,103)  G ; [103,107) M1 ; [107,115) L f32

using bf16   = __bf16;
using bf16x8 = __attribute__((ext_vector_type(8))) __bf16;
using bf16x4 = __attribute__((ext_vector_type(4))) __bf16;
using f32x4  = __attribute__((ext_vector_type(4))) float;

#define DI __device__ __forceinline__

// ---------------- 128x128 tile core, LDS XOR-swizzled ----------------
DI void gemm128_core(const bf16* __restrict__ A, long lda,
                     const bf16* __restrict__ B, long ldb,
                     int ksteps, bf16* As, bf16* Bs, f32x4 acc[4][4]) {
  const int tid  = threadIdx.x;
  const int lane = tid & 63;
  const int w    = tid >> 6;
  const int lr   = lane & 15;
  const int lk   = (lane >> 4) * 8;
  const int wr   = (w >> 1) * 64;
  const int wc   = (w & 1) * 64;
  const int sw   = (lr & 7) << 3;       // read-side XOR swizzle

  for (int kt = 0; kt < ksteps; ++kt) {
    bf16x8 av[4], bv[4];
#pragma unroll
    for (int c = 0; c < 4; ++c) {
      const int idx = c * 256 + tid;
      const int row = idx >> 3, col = (idx & 7) * 8;
      av[c] = *(const bf16x8*)(A + (long)row * lda + (long)kt * 64 + col);
      bv[c] = *(const bf16x8*)(B + (long)row * ldb + (long)kt * 64 + col);
    }
#pragma unroll
    for (int c = 0; c < 4; ++c) {
      const int idx = c * 256 + tid;
      const int row = idx >> 3;
      const int scol = ((idx & 7) * 8) ^ ((row & 7) << 3);
      *(bf16x8*)(As + row * 64 + scol) = av[c];
      *(bf16x8*)(Bs + row * 64 + scol) = bv[c];
    }
    __syncthreads();
#pragma unroll
    for (int kk = 0; kk < 2; ++kk) {
      bf16x8 af[4], bfr[4];
#pragma unroll
      for (int i = 0; i < 4; ++i)
        af[i] = *(const bf16x8*)(As + (wr + i * 16 + lr) * 64 + ((kk * 32 + lk) ^ sw));
#pragma unroll
      for (int i = 0; i < 4; ++i)
        bfr[i] = *(const bf16x8*)(Bs + (wc + i * 16 + lr) * 64 + ((kk * 32 + lk) ^ sw));
#pragma unroll
      for (int i = 0; i < 4; ++i)
#pragma unroll
        for (int j = 0; j < 4; ++j)
          acc[i][j] = __builtin_amdgcn_mfma_f32_16x16x32_bf16(af[i], bfr[j], acc[i][j], 0, 0, 0);
    }
    __syncthreads();
  }
}

// ---------------- 64x64 tile core, LDS XOR-swizzled ----------------
DI void gemm64_core(const bf16* __restrict__ A, long lda,
                    const bf16* __restrict__ B, long ldb,
                    int ksteps, bf16* As, bf16* Bs, f32x4 acc[2][2]) {
  const int tid  = threadIdx.x;
  const int lane = tid & 63;
  const int w    = tid >> 6;
  const int lr   = lane & 15;
  const int lk   = (lane >> 4) * 8;
  const int wr   = (w >> 1) * 32;
  const int wc   = (w & 1) * 32;
  const int sw   = (lr & 7) << 3;

  for (int kt = 0; kt < ksteps; ++kt) {
    bf16x8 av[2], bv[2];
#pragma unroll
    for (int c = 0; c < 2; ++c) {
      const int idx = c * 256 + tid;
      const int row = idx >> 3, col = (idx & 7) * 8;
      av[c] = *(const bf16x8*)(A + (long)row * lda + (long)kt * 64 + col);
      bv[c] = *(const bf16x8*)(B + (long)row * ldb + (long)kt * 64 + col);
    }
#pragma unroll
    for (int c = 0; c < 2; ++c) {
      const int idx = c * 256 + tid;
      const int row = idx >> 3;
      const int scol = ((idx & 7) * 8) ^ ((row & 7) << 3);
      *(bf16x8*)(As + row * 64 + scol) = av[c];
      *(bf16x8*)(Bs + row * 64 + scol) = bv[c];
    }
    __syncthreads();
#pragma unroll
    for (int kk = 0; kk < 2; ++kk) {
      bf16x8 af[2], bfr[2];
#pragma unroll
      for (int i = 0; i < 2; ++i)
        af[i] = *(const bf16x8*)(As + (wr + i * 16 + lr) * 64 + ((kk * 32 + lk) ^ sw));
#pragma unroll
      for (int i = 0; i < 2; ++i)
        bfr[i] = *(const bf16x8*)(Bs + (wc + i * 16 + lr) * 64 + ((kk * 32 + lk) ^ sw));
#pragma unroll
      for (int i = 0; i < 2; ++i)
#pragma unroll
        for (int j = 0; j < 2; ++j)
          acc[i][j] = __builtin_amdgcn_mfma_f32_16x16x32_bf16(af[i], bfr[j], acc[i][j], 0, 0, 0);
    }
    __syncthreads();
  }
}

// ---------------- GroupNorm stats ----------------
__global__ __launch_bounds__(256) void k_gnstats(const float* __restrict__ x,
                                                 float2* __restrict__ stats) {
  const int bg = blockIdx.x, b = bg >> 5, g = bg & 31;
  const float* base = x + (size_t)b * 4096 * 512 + g * 16;
  const int tid = threadIdx.x;
  float s = 0.f, ss = 0.f;
  for (int it = 0; it < 64; ++it) {
    const int idx = it * 256 + tid;
    const int p = idx >> 2, c4 = (idx & 3) * 4;
    float4 v = *(const float4*)(base + (size_t)p * 512 + c4);
    s  += v.x + v.y + v.z + v.w;
    ss += v.x * v.x + v.y * v.y + v.z * v.z + v.w * v.w;
  }
  __shared__ float rs[256], rss[256];
  rs[tid] = s; rss[tid] = ss; __syncthreads();
  for (int off = 128; off; off >>= 1) {
    if (tid < off) { rs[tid] += rs[tid + off]; rss[tid] += rss[tid + off]; }
    __syncthreads();
  }
  if (tid == 0) {
    float mean = rs[0] * (1.f / 65536.f);
    float var  = rss[0] * (1.f / 65536.f) - mean * mean;
    stats[bg] = float2{mean, rsqrtf(var + 1e-5f)};
  }
}

// ---------------- GN apply -> Hn + HnT + col-sums s ----------------
__global__ __launch_bounds__(256) void k_gnapply_t(const float* __restrict__ x,
                                                   const float2* __restrict__ stats,
                                                   const float* __restrict__ gns,
                                                   const float* __restrict__ gnb,
                                                   bf16* __restrict__ Hn,
                                                   bf16* __restrict__ HnT,
                                                   float* __restrict__ s) {
  __shared__ bf16 tile[64 * 516];
  __shared__ float cs[512];
  const int tid = threadIdx.x;
  const int blk = blockIdx.x;       // 0..511
  const int b = blk >> 6, p0 = (blk & 63) * 64;
  cs[tid] = 0.f; cs[tid + 256] = 0.f;
  __syncthreads();

  const int c4 = (tid & 127) * 4;
  const int hi = tid >> 7;
  const float2 st = stats[b * 32 + (c4 >> 4)];
  const float4 sc = *(const float4*)(gns + c4);
  const float4 bi = *(const float4*)(gnb + c4);
  float a0 = 0.f, a1 = 0.f, a2 = 0.f, a3 = 0.f;
  for (int i = 0; i < 32; ++i) {
    const int px = i * 2 + hi;
    const float4 xv = *(const float4*)(x + ((size_t)(b * 4096 + p0 + px)) * 512 + c4);
    const float h0 = (xv.x - st.x) * st.y * sc.x + bi.x;
    const float h1 = (xv.y - st.x) * st.y * sc.y + bi.y;
    const float h2 = (xv.z - st.x) * st.y * sc.z + bi.z;
    const float h3 = (xv.w - st.x) * st.y * sc.w + bi.w;
    a0 += h0; a1 += h1; a2 += h2; a3 += h3;
    bf16x4 hv;
    hv[0] = (bf16)h0; hv[1] = (bf16)h1; hv[2] = (bf16)h2; hv[3] = (bf16)h3;
    *(bf16x4*)(Hn + ((size_t)(b * 4096 + p0 + px)) * 512 + c4) = hv;
    *(bf16x4*)(tile + px * 516 + c4) = hv;
  }
  atomicAdd(&cs[c4 + 0], a0); atomicAdd(&cs[c4 + 1], a1);
  atomicAdd(&cs[c4 + 2], a2); atomicAdd(&cs[c4 + 3], a3);
  __syncthreads();
  atomicAdd(s + b * 512 + tid, cs[tid]);
  atomicAdd(s + b * 512 + 256 + tid, cs[tid + 256]);

  for (int cg = 0; cg < 16; ++cg) {
    const int c  = cg * 32 + (tid >> 3);
    const int so = (tid & 7) * 8;
    bf16x8 pk;
#pragma unroll
    for (int k = 0; k < 8; ++k) pk[k] = tile[(so + k) * 516 + c];
    *(bf16x8*)(HnT + ((size_t)(b * 512 + c)) * 4096 + p0 + so) = pk;
  }
}

// ---------------- weight transpose+cast (+ zero s, + Wv bf16 copy) ----------------
__global__ void k_wt(const float* __restrict__ wq, const float* __restrict__ wk,
                     const float* __restrict__ wv, const float* __restrict__ wp,
                     bf16* __restrict__ WT, bf16* __restrict__ wvb,
                     float* __restrict__ s) {
  __shared__ float t[32][33];
  const int z = blockIdx.z;
  const float* src = (z == 0) ? wq : (z == 1) ? wk : (z == 2) ? wv : wp;
  const int n0 = blockIdx.x * 32, k0 = blockIdx.y * 32;
  const int tx = threadIdx.x, ty = threadIdx.y;   // (32, 8)
  if (z == 0 && blockIdx.y == 0) s[blockIdx.x * 256 + ty * 32 + tx] = 0.f;
#pragma unroll
  for (int j = 0; j < 4; ++j) {
    const float v = src[(size_t)(k0 + ty + j * 8) * 512 + n0 + tx];
    t[ty + j * 8][tx] = v;
    if (z == 2) wvb[(size_t)(k0 + ty + j * 8) * 512 + n0 + tx] = (bf16)v;
  }
  __syncthreads();
#pragma unroll
  for (int j = 0; j < 4; ++j)
    WT[(size_t)(z * 512 + n0 + ty + j * 8) * 512 + k0 + tx] = (bf16)t[tx][ty + j * 8];
}

// ---------------- Gram: symmetric tiles, split-K=4, xcd==batch ----------------
__global__ __launch_bounds__(256) void k_gram(const bf16* __restrict__ HnT,
                                              float* __restrict__ part) {
  __shared__ bf16 As[128 * 64], Bs[128 * 64];
  const int Lb = blockIdx.x;           // 0..319 ; xcd = Lb%8 = batch
  const int b  = Lb & 7;
  const int idx = Lb >> 3;             // 0..39
  const int sp = idx & 3;
  const int t  = idx >> 2;             // 0..9 upper-tri tile id
  const int m0 = (int)((0x3221110000ull >> (4 * t)) & 15) * 128;
  const int n0 = (int)((0x3323213210ull >> (4 * t)) & 15) * 128;
  f32x4 acc[4][4];
#pragma unroll
  for (int i = 0; i < 4; ++i)
#pragma unroll
    for (int j = 0; j < 4; ++j) acc[i][j] = (f32x4){0.f, 0.f, 0.f, 0.f};
  const bf16* A = HnT + ((size_t)b * 512 + m0) * 4096 + sp * 1024;
  const bf16* B = HnT + ((size_t)b * 512 + n0) * 4096 + sp * 1024;
  gemm128_core(A, 4096, B, 4096, 16, As, Bs, acc);

  const int lane = threadIdx.x & 63, w = threadIdx.x >> 6;
  const int wr = (w >> 1) * 64, wc = (w & 1) * 64;
  const int rr = (lane >> 4) * 4, cc = lane & 15;
  float* dst = part + (size_t)(sp * 8 + b) * 262144;
#pragma unroll
  for (int i = 0; i < 4; ++i) {
#pragma unroll
    for (int j = 0; j < 4; ++j) {
      const int gm = m0 + wr + i * 16 + rr;
      const int gn = n0 + wc + j * 16 + cc;
      float* p = dst + (size_t)gm * 512 + gn;
      p[0]    = acc[i][j][0];
      p[512]  = acc[i][j][1];
      p[1024] = acc[i][j][2];
      p[1536] = acc[i][j][3];
      if (m0 != n0)   // mirror (G symmetric): rows gn, cols gm..gm+3
        *(f32x4*)(dst + (size_t)gn * 512 + gm) = acc[i][j];
    }
  }
}

// ---------------- reduce 4 gram partials -> bf16 G ----------------
__global__ __launch_bounds__(256) void k_gsum(const float* __restrict__ part,
                                              bf16* __restrict__ G) {
  const size_t S8 = (size_t)8 * 262144;
  const size_t i4 = ((size_t)blockIdx.x * 256 + threadIdx.x) * 4;
  const float4 a = *(const float4*)(part + i4);
  const float4 c = *(const float4*)(part + i4 + S8);
  const float4 d = *(const float4*)(part + i4 + 2 * S8);
  const float4 e = *(const float4*)(part + i4 + 3 * S8);
  bf16x4 o;
  o[0] = (bf16)(a.x + c.x + d.x + e.x); o[1] = (bf16)(a.y + c.y + d.y + e.y);
  o[2] = (bf16)(a.z + c.z + d.z + e.z); o[3] = (bf16)(a.w + c.w + d.w + e.w);
  *(bf16x4*)(G + i4) = o;
}

// ---------------- small vectors ----------------
__global__ __launch_bounds__(512) void k_vecs(const bf16* __restrict__ WT,
                                              const float* __restrict__ s,
                                              const float* __restrict__ bv,
                                              const bf16* __restrict__ T,
                                              float* __restrict__ uq,
                                              float* __restrict__ vkv,
                                              float* __restrict__ dv,
                                              int mode) {
  const int i = threadIdx.x;
  if (mode == 0) {
    const int z = blockIdx.x;
    const int which = z >> 3, b = z & 7;
    const bf16* row = WT + ((size_t)(which * 512 + i)) * 512;
    const float* sv = s + b * 512;
    float acc = 0.f;
    for (int c = 0; c < 512; ++c) acc += (float)row[c] * sv[c];
    (which == 0 ? uq : vkv)[b * 512 + i] = acc;
  } else {
    const int b = blockIdx.x;
    const bf16* row = T + (size_t)b * 262144 + (size_t)i * 512;
    float acc = 0.f;
    for (int c = 0; c < 512; ++c) acc += (float)row[c] * bv[c];
    dv[b * 512 + i] = acc;
  }
}

// ---------------- batched small GEMM 512x512x512, bf16 out ----------------
__global__ __launch_bounds__(256) void k_sg64_bf(const bf16* __restrict__ Ab, long a_bs,
                                                 const bf16* __restrict__ Bb, long b_bs,
                                                 bf16* __restrict__ Cb) {
  __shared__ bf16 As[64 * 64], Bs[64 * 64];
  const int b = blockIdx.z;
  const int m0 = blockIdx.y * 64, n0 = blockIdx.x * 64;
  f32x4 acc[2][2];
#pragma unroll
  for (int i = 0; i < 2; ++i)
#pragma unroll
    for (int j = 0; j < 2; ++j) acc[i][j] = (f32x4){0.f, 0.f, 0.f, 0.f};
  gemm64_core(Ab + (size_t)b * a_bs + (size_t)m0 * 512, 512,
              Bb + (size_t)b * b_bs + (size_t)n0 * 512, 512, 8, As, Bs, acc);

  const int lane = threadIdx.x & 63, w = threadIdx.x >> 6;
  const int wr = (w >> 1) * 32, wc = (w & 1) * 32;
  const int rr = (lane >> 4) * 4, cc = lane & 15;
  bf16* dst = Cb + (size_t)b * 262144;
#pragma unroll
  for (int i = 0; i < 2; ++i) {
#pragma unroll
    for (int j = 0; j < 2; ++j) {
      const int gm = m0 + wr + i * 16 + rr;
      const int gn = n0 + wc + j * 16 + cc;
      bf16* p = dst + (size_t)gm * 512 + gn;
      p[0]    = (bf16)acc[i][j][0];
      p[512]  = (bf16)acc[i][j][1];
      p[1024] = (bf16)acc[i][j][2];
      p[1536] = (bf16)acc[i][j][3];
    }
  }
}

// ---------------- batched small GEMM 512x512x512, fp32 out ----------------
__global__ __launch_bounds__(256) void k_sg64_f32(const bf16* __restrict__ Ab, long a_bs,
                                                  const bf16* __restrict__ Bb, long b_bs,
                                                  float* __restrict__ Cb) {
  __shared__ bf16 As[64 * 64], Bs[64 * 64];
  const int b = blockIdx.z;
  const int m0 = blockIdx.y * 64, n0 = blockIdx.x * 64;
  f32x4 acc[2][2];
#pragma unroll
  for (int i = 0; i < 2; ++i)
#pragma unroll
    for (int j = 0; j < 2; ++j) acc[i][j] = (f32x4){0.f, 0.f, 0.f, 0.f};
  gemm64_core(Ab + (size_t)b * a_bs + (size_t)m0 * 512, 512,
              Bb + (size_t)b * b_bs + (size_t)n0 * 512, 512, 8, As, Bs, acc);

  const int lane = threadIdx.x & 63, w = threadIdx.x >> 6;
  const int wr = (w >> 1) * 32, wc = (w & 1) * 32;
  const int rr = (lane >> 4) * 4, cc = lane & 15;
  float* dst = Cb + (size_t)b * 262144;
#pragma unroll
  for (int i = 0; i < 2; ++i) {
#pragma unroll
    for (int j = 0; j < 2; ++j) {
      const int gm = m0 + wr + i * 16 + rr;
      const int gn = n0 + wc + j * 16 + cc;
      float* p = dst + (size_t)gm * 512 + gn;
      p[0]    = acc[i][j][0];
      p[512]  = acc[i][j][1];
      p[1024] = acc[i][j][2];
      p[1536] = acc[i][j][3];
    }
  }
}

// ---------------- softmax rows of L (+rank-1 bias terms) -> attn bf16 ----------------
__global__ __launch_bounds__(128) void k_softmax(const float* __restrict__ L,
                                                 const float* __restrict__ uq,
                                                 const float* __restrict__ vkv,
                                                 const float* __restrict__ bq,
                                                 const float* __restrict__ bk,
                                                 bf16* __restrict__ attn) {
  const int row = blockIdx.x, tid = threadIdx.x;
  const int b = row >> 9, i = row & 511;
  const float r  = uq[b * 512 + i];
  const float q0 = bq[i];
  const float4 l  = *(const float4*)(L + (size_t)row * 512 + tid * 4);
  const float4 bk4 = *(const float4*)(bk + tid * 4);
  const float4 vk4 = *(const float4*)(vkv + b * 512 + tid * 4);
  const float v0 = l.x + r * bk4.x + q0 * (vk4.x + 4096.f * bk4.x);
  const float v1 = l.y + r * bk4.y + q0 * (vk4.y + 4096.f * bk4.y);
  const float v2 = l.z + r * bk4.z + q0 * (vk4.z + 4096.f * bk4.z);
  const float v3 = l.w + r * bk4.w + q0 * (vk4.w + 4096.f * bk4.w);
  __shared__ float red[128];
  red[tid] = fmaxf(fmaxf(v0, v1), fmaxf(v2, v3));
  __syncthreads();
  for (int off = 64; off; off >>= 1) {
    if (tid < off) red[tid] = fmaxf(red[tid], red[tid + off]);
    __syncthreads();
  }
  const float M = red[0];
  __syncthreads();
  const float e0 = __expf(v0 - M), e1 = __expf(v1 - M);
  const float e2 = __expf(v2 - M), e3 = __expf(v3 - M);
  red[tid] = e0 + e1 + e2 + e3;
  __syncthreads();
  for (int off = 64; off; off >>= 1) {
    if (tid < off) red[tid] += red[tid + off];
    __syncthreads();
  }
  const float inv = 1.f / red[0];
  bf16x4 o;
  o[0] = (bf16)(e0 * inv); o[1] = (bf16)(e1 * inv);
  o[2] = (bf16)(e2 * inv); o[3] = (bf16)(e3 * inv);
  *(bf16x4*)(attn + (size_t)row * 512 + tid * 4) = o;
}

// ---------------- attn transpose per batch ----------------
__global__ void k_att_t(const bf16* __restrict__ attn, bf16* __restrict__ attnT) {
  __shared__ bf16 t[32][33];
  const int b = blockIdx.z;
  const int n0 = blockIdx.x * 32, k0 = blockIdx.y * 32;
  const int tx = threadIdx.x, ty = threadIdx.y;
#pragma unroll
  for (int j = 0; j < 4; ++j)
    t[ty + j * 8][tx] = attn[(size_t)b * 262144 + (size_t)(k0 + ty + j * 8) * 512 + n0 + tx];
  __syncthreads();
#pragma unroll
  for (int j = 0; j < 4; ++j)
    attnT[(size_t)b * 262144 + (size_t)(n0 + ty + j * 8) * 512 + k0 + tx] = t[tx][ty + j * 8];
}

// ---------------- final: out = x + Hn C_b + d_b + bp ; xcd==batch grid ----------------
__global__ __launch_bounds__(256) void k_final(const bf16* __restrict__ Hn,
                                               const bf16* __restrict__ CT,
                                               const float* __restrict__ dv,
                                               const float* __restrict__ bp,
                                               const float* __restrict__ x,
                                               float* __restrict__ out) {
  __shared__ bf16 As[128 * 64], Bs[128 * 64];
  const int Lb = blockIdx.x;           // 0..1023 ; xcd = Lb%8 = batch
  const int b  = Lb & 7;
  const int idx = Lb >> 3;             // 0..127
  const int m0 = (idx >> 2) * 128;
  const int n0 = (idx & 3) * 128;
  f32x4 acc[4][4];
#pragma unroll
  for (int i = 0; i < 4; ++i)
#pragma unroll
    for (int j = 0; j < 4; ++j) acc[i][j] = (f32x4){0.f, 0.f, 0.f, 0.f};
  gemm128_core(Hn + ((size_t)b * 4096 + m0) * 512, 512,
               CT + (size_t)b * 262144 + (size_t)n0 * 512, 512, 8, As, Bs, acc);

  const int lane = threadIdx.x & 63, w = threadIdx.x >> 6;
  const int wr = (w >> 1) * 64, wc = (w & 1) * 64;
  const int rr = (lane >> 4) * 4, cc = lane & 15;
#pragma unroll
  for (int i = 0; i < 4; ++i) {
#pragma unroll
    for (int j = 0; j < 4; ++j) {
      const int gm = m0 + wr + i * 16 + rr;
      const int gn = n0 + wc + j * 16 + cc;
      const float add = dv[b * 512 + gn] + bp[gn];
#pragma unroll
      for (int jj = 0; jj < 4; ++jj) {
        const size_t off = ((size_t)(b * 4096 + gm + jj)) * 512 + gn;
        out[off] = acc[i][j][jj] + add + x[off];
      }
    }
  }
}

extern "C" void kernel_launch(void* const* d_in, const int* in_sizes, int n_in,
                              void* d_out, int out_size, void* d_ws, size_t ws_size,
                              hipStream_t stream) {
  const float* x   = (const float*)d_in[0];
  const float* wq  = (const float*)d_in[1];
  const float* bq  = (const float*)d_in[2];
  const float* wk  = (const float*)d_in[3];
  const float* bk  = (const float*)d_in[4];
  const float* wv  = (const float*)d_in[5];
  const float* bv  = (const float*)d_in[6];
  const float* wp  = (const float*)d_in[7];
  const float* bp  = (const float*)d_in[8];
  const float* gns = (const float*)d_in[9];
  const float* gnb = (const float*)d_in[10];
  float* out = (float*)d_out;

  const size_t MB = 1ull << 20;
  const size_t KB = 1024;
  char* wsb = (char*)d_ws;
  bf16*   WT    = (bf16*)(wsb);                       // 2 MB
  bf16*   wvb   = (bf16*)(wsb + 2 * MB);              // 512 KB
  float2* stats = (float2*)(wsb + 2 * MB + 512 * KB);
  float*  s     = (float*)(wsb + 2 * MB + 576 * KB);
  float*  uq    = (float*)(wsb + 2 * MB + 640 * KB);
  float*  vkv   = (float*)(wsb + 2 * MB + 704 * KB);
  float*  dv    = (float*)(wsb + 2 * MB + 768 * KB);
  bf16*   Hn    = (bf16*)(wsb + 3 * MB);              // 32 MB
  bf16*   HnT   = (bf16*)(wsb + 35 * MB);             // 32 MB
  float*  part  = (float*)(wsb + 67 * MB);            // 32 MB [4][8][512][512]
  bf16*   attn  = (bf16*)(wsb + 67 * MB);             // overlay (part dead after gsum)
  bf16*   attnT = (bf16*)(wsb + 71 * MB);
  bf16*   T     = (bf16*)(wsb + 75 * MB);
  bf16*   CT    = (bf16*)(wsb + 79 * MB);
  bf16*   G     = (bf16*)(wsb + 99 * MB);             // 4 MB
  bf16*   M1    = (bf16*)(wsb + 103 * MB);            // 4 MB
  float*  L     = (float*)(wsb + 107 * MB);           // 8 MB

  const long S2 = 512 * 512;

  k_wt        <<<dim3(16, 16, 4), dim3(32, 8), 0, stream>>>(wq, wk, wv, wp, WT, wvb, s);
  k_gnstats   <<<dim3(256),       dim3(256),   0, stream>>>(x, stats);
  k_gnapply_t <<<dim3(512),       dim3(256),   0, stream>>>(x, stats, gns, gnb, Hn, HnT, s);
  k_gram      <<<dim3(320),       dim3(256),   0, stream>>>(HnT, part);
  k_gsum      <<<dim3(2048),      dim3(256),   0, stream>>>(part, G);
  k_vecs      <<<dim3(16),        dim3(512),   0, stream>>>(WT, s, bv, T, uq, vkv, dv, 0);
  k_sg64_bf   <<<dim3(8, 8, 8),   dim3(256),   0, stream>>>(WT, 0, G, S2, M1);
  k_sg64_f32  <<<dim3(8, 8, 8),   dim3(256),   0, stream>>>(M1, S2, WT + (size_t)512 * 512, 0, L);
  k_softmax   <<<dim3(4096),      dim3(128),   0, stream>>>(L, uq, vkv, bq, bk, attn);
  k_att_t     <<<dim3(16, 16, 8), dim3(32, 8), 0, stream>>>(attn, attnT);
  k_sg64_bf   <<<dim3(8, 8, 8),   dim3(256),   0, stream>>>(WT + (size_t)3 * 512 * 512, 0, attnT, S2, T);
  k_vecs      <<<dim3(8),         dim3(512),   0, stream>>>(WT, s, bv, T, uq, vkv, dv, 1);
  k_sg64_bf   <<<dim3(8, 8, 8),   dim3(256),   0, stream>>>(T, S2, wvb, 0, CT);
  k_final     <<<dim3(1024),      dim3(256),   0, stream>>>(Hn, CT, dv, bp, x, out);
}

// Round 7
// 192.225 us; speedup vs baseline: 1.4477x; 1.0180x over previous
//
#include <hip/hip_runtime.h>
#include <hip/hip_bf16.h>

// SelfAttention (channel attention) on MI355X. Inputs fp32, OUTPUT fp32.
//   Hn = GN(x) (bf16, never materialized row-major; HnT only)
//   G_b = Hn_b^T Hn_b ; L_b = Wq^T G_b Wk + rank-1 bias terms
//   attn_b = softmax_rows(L_b) ; attnbv[k] = attn_b[k,:]·bv
//   CT_b = (Wp^T attn_b) Wv^T ; dv = Wp^T attnbv
//   out = x + GN(x) CT_b^T + dv + bp   (GN recomputed inline in final GEMM)
// gemm(A,B): C[m][n] = sum_k A[m][k]*B[n][k] (both K-contiguous).
// R7: Hn buffer removed (inline GN in k_final); 14 -> 10 dispatches
//     (wt+gnstats, gsum+vecs0, softmax+transpose+attnbv, dv folded into final).
// Workspace:
//   [0,2)MB WT[2048][512]bf16 ; [2,2.5) wvb ; 2.5MB stats ; +64K s ; +128K uq ;
//   +192K vkv ; +832K attnbv[8][512]f32
//   [35,67) HnT [8][512][4096] bf16
//   [67,99) part [4][8][512][512] f32 -> later attnT(67) T(71) CT(75)
//   [99,103) G ; [103,107) M1 ; [107,115) L f32

using bf16   = __bf16;
using bf16x8 = __attribute__((ext_vector_type(8))) __bf16;
using bf16x4 = __attribute__((ext_vector_type(4))) __bf16;
using f32x4  = __attribute__((ext_vector_type(4))) float;

#define DI __device__ __forceinline__

// ---------------- 128x128 tile core, LDS XOR-swizzled ----------------
DI void gemm128_core(const bf16* __restrict__ A, long lda,
                     const bf16* __restrict__ B, long ldb,
                     int ksteps, bf16* As, bf16* Bs, f32x4 acc[4][4]) {
  const int tid  = threadIdx.x;
  const int lane = tid & 63;
  const int w    = tid >> 6;
  const int lr   = lane & 15;
  const int lk   = (lane >> 4) * 8;
  const int wr   = (w >> 1) * 64;
  const int wc   = (w & 1) * 64;
  const int sw   = (lr & 7) << 3;

  for (int kt = 0; kt < ksteps; ++kt) {
    bf16x8 av[4], bv[4];
#pragma unroll
    for (int c = 0; c < 4; ++c) {
      const int idx = c * 256 + tid;
      const int row = idx >> 3, col = (idx & 7) * 8;
      av[c] = *(const bf16x8*)(A + (long)row * lda + (long)kt * 64 + col);
      bv[c] = *(const bf16x8*)(B + (long)row * ldb + (long)kt * 64 + col);
    }
#pragma unroll
    for (int c = 0; c < 4; ++c) {
      const int idx = c * 256 + tid;
      const int row = idx >> 3;
      const int scol = ((idx & 7) * 8) ^ ((row & 7) << 3);
      *(bf16x8*)(As + row * 64 + scol) = av[c];
      *(bf16x8*)(Bs + row * 64 + scol) = bv[c];
    }
    __syncthreads();
#pragma unroll
    for (int kk = 0; kk < 2; ++kk) {
      bf16x8 af[4], bfr[4];
#pragma unroll
      for (int i = 0; i < 4; ++i)
        af[i] = *(const bf16x8*)(As + (wr + i * 16 + lr) * 64 + ((kk * 32 + lk) ^ sw));
#pragma unroll
      for (int i = 0; i < 4; ++i)
        bfr[i] = *(const bf16x8*)(Bs + (wc + i * 16 + lr) * 64 + ((kk * 32 + lk) ^ sw));
#pragma unroll
      for (int i = 0; i < 4; ++i)
#pragma unroll
        for (int j = 0; j < 4; ++j)
          acc[i][j] = __builtin_amdgcn_mfma_f32_16x16x32_bf16(af[i], bfr[j], acc[i][j], 0, 0, 0);
    }
    __syncthreads();
  }
}

// ---------------- 64x64 tile core, LDS XOR-swizzled ----------------
DI void gemm64_core(const bf16* __restrict__ A, long lda,
                    const bf16* __restrict__ B, long ldb,
                    int ksteps, bf16* As, bf16* Bs, f32x4 acc[2][2]) {
  const int tid  = threadIdx.x;
  const int lane = tid & 63;
  const int w    = tid >> 6;
  const int lr   = lane & 15;
  const int lk   = (lane >> 4) * 8;
  const int wr   = (w >> 1) * 32;
  const int wc   = (w & 1) * 32;
  const int sw   = (lr & 7) << 3;

  for (int kt = 0; kt < ksteps; ++kt) {
    bf16x8 av[2], bv[2];
#pragma unroll
    for (int c = 0; c < 2; ++c) {
      const int idx = c * 256 + tid;
      const int row = idx >> 3, col = (idx & 7) * 8;
      av[c] = *(const bf16x8*)(A + (long)row * lda + (long)kt * 64 + col);
      bv[c] = *(const bf16x8*)(B + (long)row * ldb + (long)kt * 64 + col);
    }
#pragma unroll
    for (int c = 0; c < 2; ++c) {
      const int idx = c * 256 + tid;
      const int row = idx >> 3;
      const int scol = ((idx & 7) * 8) ^ ((row & 7) << 3);
      *(bf16x8*)(As + row * 64 + scol) = av[c];
      *(bf16x8*)(Bs + row * 64 + scol) = bv[c];
    }
    __syncthreads();
#pragma unroll
    for (int kk = 0; kk < 2; ++kk) {
      bf16x8 af[2], bfr[2];
#pragma unroll
      for (int i = 0; i < 2; ++i)
        af[i] = *(const bf16x8*)(As + (wr + i * 16 + lr) * 64 + ((kk * 32 + lk) ^ sw));
#pragma unroll
      for (int i = 0; i < 2; ++i)
        bfr[i] = *(const bf16x8*)(Bs + (wc + i * 16 + lr) * 64 + ((kk * 32 + lk) ^ sw));
#pragma unroll
      for (int i = 0; i < 2; ++i)
#pragma unroll
        for (int j = 0; j < 2; ++j)
          acc[i][j] = __builtin_amdgcn_mfma_f32_16x16x32_bf16(af[i], bfr[j], acc[i][j], 0, 0, 0);
    }
    __syncthreads();
  }
}

// ---------------- prep: GN stats (blocks 0..255) + weight transpose (256..1279) ----------------
__global__ __launch_bounds__(256) void k_prep(const float* __restrict__ x,
                                              const float* __restrict__ wq,
                                              const float* __restrict__ wk,
                                              const float* __restrict__ wv,
                                              const float* __restrict__ wp,
                                              bf16* __restrict__ WT,
                                              bf16* __restrict__ wvb,
                                              float* __restrict__ s,
                                              float2* __restrict__ stats) {
  __shared__ float shm[1056];
  const int tid = threadIdx.x;
  const int bx = blockIdx.x;
  if (bx < 256) {
    const int b = bx >> 5, g = bx & 31;
    const float* base = x + (size_t)b * 4096 * 512 + g * 16;
    float sm = 0.f, ss = 0.f;
    for (int it = 0; it < 64; ++it) {
      const int idx = it * 256 + tid;
      const int p = idx >> 2, c4 = (idx & 3) * 4;
      float4 v = *(const float4*)(base + (size_t)p * 512 + c4);
      sm += v.x + v.y + v.z + v.w;
      ss += v.x * v.x + v.y * v.y + v.z * v.z + v.w * v.w;
    }
    float* rs = shm; float* rss = shm + 256;
    rs[tid] = sm; rss[tid] = ss; __syncthreads();
    for (int off = 128; off; off >>= 1) {
      if (tid < off) { rs[tid] += rs[tid + off]; rss[tid] += rss[tid + off]; }
      __syncthreads();
    }
    if (tid == 0) {
      float mean = rs[0] * (1.f / 65536.f);
      float var  = rss[0] * (1.f / 65536.f) - mean * mean;
      stats[bx] = float2{mean, rsqrtf(var + 1e-5f)};
    }
  } else {
    const int r = bx - 256;             // 0..1023
    const int z = r >> 8;
    const int r2 = r & 255;
    const int bxx = r2 & 15, byy = r2 >> 4;
    const int tx = tid & 31, ty = tid >> 5;
    const float* src = (z == 0) ? wq : (z == 1) ? wk : (z == 2) ? wv : wp;
    const int n0 = bxx * 32, k0 = byy * 32;
    if (z == 0 && byy == 0) s[bxx * 256 + tid] = 0.f;
#pragma unroll
    for (int j = 0; j < 4; ++j) {
      const float v = src[(size_t)(k0 + ty + j * 8) * 512 + n0 + tx];
      shm[(ty + j * 8) * 33 + tx] = v;
      if (z == 2) wvb[(size_t)(k0 + ty + j * 8) * 512 + n0 + tx] = (bf16)v;
    }
    __syncthreads();
#pragma unroll
    for (int j = 0; j < 4; ++j)
      WT[(size_t)(z * 512 + n0 + ty + j * 8) * 512 + k0 + tx] = (bf16)shm[tx * 33 + ty + j * 8];
  }
}

// ---------------- GN apply -> HnT (transposed only) + col-sums s ----------------
__global__ __launch_bounds__(256) void k_gnapply_t(const float* __restrict__ x,
                                                   const float2* __restrict__ stats,
                                                   const float* __restrict__ gns,
                                                   const float* __restrict__ gnb,
                                                   bf16* __restrict__ HnT,
                                                   float* __restrict__ s) {
  __shared__ bf16 tile[64 * 516];
  __shared__ float cs[512];
  const int tid = threadIdx.x;
  const int blk = blockIdx.x;       // 0..511
  const int b = blk >> 6, p0 = (blk & 63) * 64;
  cs[tid] = 0.f; cs[tid + 256] = 0.f;
  __syncthreads();

  const int c4 = (tid & 127) * 4;
  const int hi = tid >> 7;
  const float2 st = stats[b * 32 + (c4 >> 4)];
  const float4 sc = *(const float4*)(gns + c4);
  const float4 bi = *(const float4*)(gnb + c4);
  float a0 = 0.f, a1 = 0.f, a2 = 0.f, a3 = 0.f;
  for (int i = 0; i < 32; ++i) {
    const int px = i * 2 + hi;
    const float4 xv = *(const float4*)(x + ((size_t)(b * 4096 + p0 + px)) * 512 + c4);
    const float h0 = (xv.x - st.x) * st.y * sc.x + bi.x;
    const float h1 = (xv.y - st.x) * st.y * sc.y + bi.y;
    const float h2 = (xv.z - st.x) * st.y * sc.z + bi.z;
    const float h3 = (xv.w - st.x) * st.y * sc.w + bi.w;
    a0 += h0; a1 += h1; a2 += h2; a3 += h3;
    bf16x4 hv;
    hv[0] = (bf16)h0; hv[1] = (bf16)h1; hv[2] = (bf16)h2; hv[3] = (bf16)h3;
    *(bf16x4*)(tile + px * 516 + c4) = hv;
  }
  atomicAdd(&cs[c4 + 0], a0); atomicAdd(&cs[c4 + 1], a1);
  atomicAdd(&cs[c4 + 2], a2); atomicAdd(&cs[c4 + 3], a3);
  __syncthreads();
  atomicAdd(s + b * 512 + tid, cs[tid]);
  atomicAdd(s + b * 512 + 256 + tid, cs[tid + 256]);

  for (int cg = 0; cg < 16; ++cg) {
    const int c  = cg * 32 + (tid >> 3);
    const int so = (tid & 7) * 8;
    bf16x8 pk;
#pragma unroll
    for (int k = 0; k < 8; ++k) pk[k] = tile[(so + k) * 516 + c];
    *(bf16x8*)(HnT + ((size_t)(b * 512 + c)) * 4096 + p0 + so) = pk;
  }
}

// ---------------- Gram: symmetric tiles, split-K=4, xcd==batch ----------------
__global__ __launch_bounds__(256) void k_gram(const bf16* __restrict__ HnT,
                                              float* __restrict__ part) {
  __shared__ bf16 As[128 * 64], Bs[128 * 64];
  const int Lb = blockIdx.x;           // 0..319 ; xcd = Lb%8 = batch
  const int b  = Lb & 7;
  const int idx = Lb >> 3;             // 0..39
  const int sp = idx & 3;
  const int t  = idx >> 2;             // 0..9 upper-tri tile id
  const int m0 = (int)((0x3221110000ull >> (4 * t)) & 15) * 128;
  const int n0 = (int)((0x3323213210ull >> (4 * t)) & 15) * 128;
  f32x4 acc[4][4];
#pragma unroll
  for (int i = 0; i < 4; ++i)
#pragma unroll
    for (int j = 0; j < 4; ++j) acc[i][j] = (f32x4){0.f, 0.f, 0.f, 0.f};
  const bf16* A = HnT + ((size_t)b * 512 + m0) * 4096 + sp * 1024;
  const bf16* B = HnT + ((size_t)b * 512 + n0) * 4096 + sp * 1024;
  gemm128_core(A, 4096, B, 4096, 16, As, Bs, acc);

  const int lane = threadIdx.x & 63, w = threadIdx.x >> 6;
  const int wr = (w >> 1) * 64, wc = (w & 1) * 64;
  const int rr = (lane >> 4) * 4, cc = lane & 15;
  float* dst = part + (size_t)(sp * 8 + b) * 262144;
#pragma unroll
  for (int i = 0; i < 4; ++i) {
#pragma unroll
    for (int j = 0; j < 4; ++j) {
      const int gm = m0 + wr + i * 16 + rr;
      const int gn = n0 + wc + j * 16 + cc;
      float* p = dst + (size_t)gm * 512 + gn;
      p[0]    = acc[i][j][0];
      p[512]  = acc[i][j][1];
      p[1024] = acc[i][j][2];
      p[1536] = acc[i][j][3];
      if (m0 != n0)
        *(f32x4*)(dst + (size_t)gn * 512 + gm) = acc[i][j];
    }
  }
}

// ---------------- gsum (blocks 0..2047) + uq/vkv small gemv (2048..2063) ----------------
__global__ __launch_bounds__(256) void k_gsumv(const float* __restrict__ part,
                                               bf16* __restrict__ G,
                                               const bf16* __restrict__ WT,
                                               const float* __restrict__ s,
                                               float* __restrict__ uq,
                                               float* __restrict__ vkv) {
  const int bx = blockIdx.x, tid = threadIdx.x;
  if (bx < 2048) {
    const size_t S8 = (size_t)8 * 262144;
    const size_t i4 = ((size_t)bx * 256 + tid) * 4;
    const float4 a = *(const float4*)(part + i4);
    const float4 c = *(const float4*)(part + i4 + S8);
    const float4 d = *(const float4*)(part + i4 + 2 * S8);
    const float4 e = *(const float4*)(part + i4 + 3 * S8);
    bf16x4 o;
    o[0] = (bf16)(a.x + c.x + d.x + e.x); o[1] = (bf16)(a.y + c.y + d.y + e.y);
    o[2] = (bf16)(a.z + c.z + d.z + e.z); o[3] = (bf16)(a.w + c.w + d.w + e.w);
    *(bf16x4*)(G + i4) = o;
  } else {
    const int z = bx - 2048;            // 0..15
    const int which = z >> 3, b = z & 7;
    const float* sv = s + b * 512;
    for (int o = tid; o < 512; o += 256) {
      const bf16* row = WT + ((size_t)(which * 512 + o)) * 512;
      float acc = 0.f;
      for (int c = 0; c < 512; c += 8) {
        bf16x8 v = *(const bf16x8*)(row + c);
        const float4 s0 = *(const float4*)(sv + c);
        const float4 s1 = *(const float4*)(sv + c + 4);
        acc += (float)v[0] * s0.x + (float)v[1] * s0.y + (float)v[2] * s0.z +
               (float)v[3] * s0.w + (float)v[4] * s1.x + (float)v[5] * s1.y +
               (float)v[6] * s1.z + (float)v[7] * s1.w;
      }
      (which == 0 ? uq : vkv)[b * 512 + o] = acc;
    }
  }
}

// ---------------- batched small GEMM 512x512x512, bf16 out ----------------
__global__ __launch_bounds__(256) void k_sg64_bf(const bf16* __restrict__ Ab, long a_bs,
                                                 const bf16* __restrict__ Bb, long b_bs,
                                                 bf16* __restrict__ Cb) {
  __shared__ bf16 As[64 * 64], Bs[64 * 64];
  const int b = blockIdx.z;
  const int m0 = blockIdx.y * 64, n0 = blockIdx.x * 64;
  f32x4 acc[2][2];
#pragma unroll
  for (int i = 0; i < 2; ++i)
#pragma unroll
    for (int j = 0; j < 2; ++j) acc[i][j] = (f32x4){0.f, 0.f, 0.f, 0.f};
  gemm64_core(Ab + (size_t)b * a_bs + (size_t)m0 * 512, 512,
              Bb + (size_t)b * b_bs + (size_t)n0 * 512, 512, 8, As, Bs, acc);

  const int lane = threadIdx.x & 63, w = threadIdx.x >> 6;
  const int wr = (w >> 1) * 32, wc = (w & 1) * 32;
  const int rr = (lane >> 4) * 4, cc = lane & 15;
  bf16* dst = Cb + (size_t)b * 262144;
#pragma unroll
  for (int i = 0; i < 2; ++i) {
#pragma unroll
    for (int j = 0; j < 2; ++j) {
      const int gm = m0 + wr + i * 16 + rr;
      const int gn = n0 + wc + j * 16 + cc;
      bf16* p = dst + (size_t)gm * 512 + gn;
      p[0]    = (bf16)acc[i][j][0];
      p[512]  = (bf16)acc[i][j][1];
      p[1024] = (bf16)acc[i][j][2];
      p[1536] = (bf16)acc[i][j][3];
    }
  }
}

// ---------------- batched small GEMM 512x512x512, fp32 out ----------------
__global__ __launch_bounds__(256) void k_sg64_f32(const bf16* __restrict__ Ab, long a_bs,
                                                  const bf16* __restrict__ Bb, long b_bs,
                                                  float* __restrict__ Cb) {
  __shared__ bf16 As[64 * 64], Bs[64 * 64];
  const int b = blockIdx.z;
  const int m0 = blockIdx.y * 64, n0 = blockIdx.x * 64;
  f32x4 acc[2][2];
#pragma unroll
  for (int i = 0; i < 2; ++i)
#pragma unroll
    for (int j = 0; j < 2; ++j) acc[i][j] = (f32x4){0.f, 0.f, 0.f, 0.f};
  gemm64_core(Ab + (size_t)b * a_bs + (size_t)m0 * 512, 512,
              Bb + (size_t)b * b_bs + (size_t)n0 * 512, 512, 8, As, Bs, acc);

  const int lane = threadIdx.x & 63, w = threadIdx.x >> 6;
  const int wr = (w >> 1) * 32, wc = (w & 1) * 32;
  const int rr = (lane >> 4) * 4, cc = lane & 15;
  float* dst = Cb + (size_t)b * 262144;
#pragma unroll
  for (int i = 0; i < 2; ++i) {
#pragma unroll
    for (int j = 0; j < 2; ++j) {
      const int gm = m0 + wr + i * 16 + rr;
      const int gn = n0 + wc + j * 16 + cc;
      float* p = dst + (size_t)gm * 512 + gn;
      p[0]    = acc[i][j][0];
      p[512]  = acc[i][j][1];
      p[1024] = acc[i][j][2];
      p[1536] = acc[i][j][3];
    }
  }
}

// ---------------- softmax (4 rows/block, wave-shuffle) -> attnT + attnbv ----------------
__global__ __launch_bounds__(256) void k_smax(const float* __restrict__ L,
                                              const float* __restrict__ uq,
                                              const float* __restrict__ vkv,
                                              const float* __restrict__ bq,
                                              const float* __restrict__ bk,
                                              const float* __restrict__ bv,
                                              bf16* __restrict__ attnT,
                                              float* __restrict__ attnbv) {
  __shared__ bf16 p[4][512];
  const int tid = threadIdx.x;
  const int w = tid >> 6, l = tid & 63;
  const int blk = blockIdx.x;          // 0..1023, 4 rows each
  const int gr = blk * 4 + w;          // global row
  const int b = gr >> 9, i = gr & 511;
  const int c = l * 8;

  const float r  = uq[b * 512 + i];
  const float q0 = bq[i];
  const float* lp = L + (size_t)gr * 512 + c;
  const float4 l0 = *(const float4*)lp;
  const float4 l1 = *(const float4*)(lp + 4);
  const float4 k0 = *(const float4*)(bk + c);
  const float4 k1 = *(const float4*)(bk + c + 4);
  const float4 g0 = *(const float4*)(vkv + b * 512 + c);
  const float4 g1 = *(const float4*)(vkv + b * 512 + c + 4);
  float v[8];
  v[0] = l0.x + r * k0.x + q0 * (g0.x + 4096.f * k0.x);
  v[1] = l0.y + r * k0.y + q0 * (g0.y + 4096.f * k0.y);
  v[2] = l0.z + r * k0.z + q0 * (g0.z + 4096.f * k0.z);
  v[3] = l0.w + r * k0.w + q0 * (g0.w + 4096.f * k0.w);
  v[4] = l1.x + r * k1.x + q0 * (g1.x + 4096.f * k1.x);
  v[5] = l1.y + r * k1.y + q0 * (g1.y + 4096.f * k1.y);
  v[6] = l1.z + r * k1.z + q0 * (g1.z + 4096.f * k1.z);
  v[7] = l1.w + r * k1.w + q0 * (g1.w + 4096.f * k1.w);

  float mx = v[0];
#pragma unroll
  for (int j = 1; j < 8; ++j) mx = fmaxf(mx, v[j]);
  for (int off = 32; off; off >>= 1) mx = fmaxf(mx, __shfl_xor(mx, off));
  float e[8], sm = 0.f;
#pragma unroll
  for (int j = 0; j < 8; ++j) { e[j] = __expf(v[j] - mx); sm += e[j]; }
  for (int off = 32; off; off >>= 1) sm += __shfl_xor(sm, off);
  const float inv = 1.f / sm;

  const float4 b0 = *(const float4*)(bv + c);
  const float4 b1 = *(const float4*)(bv + c + 4);
  float ab = e[0] * b0.x + e[1] * b0.y + e[2] * b0.z + e[3] * b0.w +
             e[4] * b1.x + e[5] * b1.y + e[6] * b1.z + e[7] * b1.w;
  ab *= inv;
  for (int off = 32; off; off >>= 1) ab += __shfl_xor(ab, off);
  if (l == 0) attnbv[gr] = ab;

  bf16x8 o;
#pragma unroll
  for (int j = 0; j < 8; ++j) o[j] = (bf16)(e[j] * inv);
  *(bf16x8*)(&p[w][c]) = o;
  __syncthreads();

  const int i0 = (blk * 4) & 511;
  for (int n = tid; n < 512; n += 256) {
    bf16x4 t;
    t[0] = p[0][n]; t[1] = p[1][n]; t[2] = p[2][n]; t[3] = p[3][n];
    *(bf16x4*)(attnT + (size_t)b * 262144 + (size_t)n * 512 + i0) = t;
  }
}

// ---------------- final: out = x + GN(x) CT^T + dv + bp ; inline GN; xcd==batch ----------------
__global__ __launch_bounds__(256) void k_final(const float* __restrict__ x,
                                               const bf16* __restrict__ CT,
                                               const float* __restrict__ attnbv,
                                               const bf16* __restrict__ WTp,
                                               const float* __restrict__ gns,
                                               const float* __restrict__ gnb,
                                               const float2* __restrict__ stats,
                                               const float* __restrict__ bp,
                                               float* __restrict__ out) {
  __shared__ bf16 As[128 * 64], Bs[128 * 64];
  __shared__ float gsc[512], gbs[512], abvs[512], dvs[128];
  const int Lb = blockIdx.x;           // 0..1023 ; xcd = Lb%8 = batch
  const int b  = Lb & 7;
  const int idx = Lb >> 3;
  const int m0 = (idx >> 2) * 128;
  const int n0 = (idx & 3) * 128;
  const int tid = threadIdx.x;

  for (int cch = tid; cch < 512; cch += 256) {
    const float2 st = stats[b * 32 + (cch >> 4)];
    const float a = st.y * gns[cch];
    gsc[cch] = a;
    gbs[cch] = gnb[cch] - st.x * a;
    abvs[cch] = attnbv[b * 512 + cch];
  }
  __syncthreads();
  if (tid < 128) {                     // dv for columns n0..n0+127
    const bf16* wrow = WTp + (size_t)(n0 + tid) * 512;
    float acc = 0.f;
    for (int k = 0; k < 512; k += 8) {
      bf16x8 v = *(const bf16x8*)(wrow + k);
#pragma unroll
      for (int j = 0; j < 8; ++j) acc += (float)v[j] * abvs[k + j];
    }
    dvs[tid] = acc;
  }

  const int lane = tid & 63, w = tid >> 6;
  const int lr = lane & 15, lk = (lane >> 4) * 8;
  const int wr2 = (w >> 1) * 64, wc = (w & 1) * 64;
  const int sw = (lr & 7) << 3;
  f32x4 acc[4][4];
#pragma unroll
  for (int i = 0; i < 4; ++i)
#pragma unroll
    for (int j = 0; j < 4; ++j) acc[i][j] = (f32x4){0.f, 0.f, 0.f, 0.f};

  const bf16* Bg = CT + (size_t)b * 262144 + (size_t)n0 * 512;
  for (int kt = 0; kt < 8; ++kt) {
    bf16x8 av[4], bv[4];
#pragma unroll
    for (int c = 0; c < 4; ++c) {
      const int idx2 = c * 256 + tid;
      const int row = idx2 >> 3;
      const int ch  = kt * 64 + (idx2 & 7) * 8;
      const float* xp = x + ((size_t)(b * 4096 + m0 + row)) * 512 + ch;
      const float4 x0 = *(const float4*)xp;
      const float4 x1 = *(const float4*)(xp + 4);
      const float4 s0 = *(const float4*)(gsc + ch);
      const float4 s1 = *(const float4*)(gsc + ch + 4);
      const float4 c0 = *(const float4*)(gbs + ch);
      const float4 c1 = *(const float4*)(gbs + ch + 4);
      av[c][0] = (bf16)(x0.x * s0.x + c0.x);
      av[c][1] = (bf16)(x0.y * s0.y + c0.y);
      av[c][2] = (bf16)(x0.z * s0.z + c0.z);
      av[c][3] = (bf16)(x0.w * s0.w + c0.w);
      av[c][4] = (bf16)(x1.x * s1.x + c1.x);
      av[c][5] = (bf16)(x1.y * s1.y + c1.y);
      av[c][6] = (bf16)(x1.z * s1.z + c1.z);
      av[c][7] = (bf16)(x1.w * s1.w + c1.w);
      bv[c] = *(const bf16x8*)(Bg + (size_t)row * 512 + ch);
    }
#pragma unroll
    for (int c = 0; c < 4; ++c) {
      const int idx2 = c * 256 + tid;
      const int row = idx2 >> 3;
      const int scol = ((idx2 & 7) * 8) ^ ((row & 7) << 3);
      *(bf16x8*)(As + row * 64 + scol) = av[c];
      *(bf16x8*)(Bs + row * 64 + scol) = bv[c];
    }
    __syncthreads();
#pragma unroll
    for (int kk = 0; kk < 2; ++kk) {
      bf16x8 af[4], bfr[4];
#pragma unroll
      for (int i = 0; i < 4; ++i)
        af[i] = *(const bf16x8*)(As + (wr2 + i * 16 + lr) * 64 + ((kk * 32 + lk) ^ sw));
#pragma unroll
      for (int i = 0; i < 4; ++i)
        bfr[i] = *(const bf16x8*)(Bs + (wc + i * 16 + lr) * 64 + ((kk * 32 + lk) ^ sw));
#pragma unroll
      for (int i = 0; i < 4; ++i)
#pragma unroll
        for (int j = 0; j < 4; ++j)
          acc[i][j] = __builtin_amdgcn_mfma_f32_16x16x32_bf16(af[i], bfr[j], acc[i][j], 0, 0, 0);
    }
    __syncthreads();
  }

  const int rr = (lane >> 4) * 4, cc = lane & 15;
#pragma unroll
  for (int i = 0; i < 4; ++i) {
#pragma unroll
    for (int j = 0; j < 4; ++j) {
      const int gm = m0 + wr2 + i * 16 + rr;
      const int gn = n0 + wc + j * 16 + cc;
      const float add = dvs[gn - n0] + bp[gn];
#pragma unroll
      for (int jj = 0; jj < 4; ++jj) {
        const size_t off = ((size_t)(b * 4096 + gm + jj)) * 512 + gn;
        out[off] = acc[i][j][jj] + add + x[off];
      }
    }
  }
}

extern "C" void kernel_launch(void* const* d_in, const int* in_sizes, int n_in,
                              void* d_out, int out_size, void* d_ws, size_t ws_size,
                              hipStream_t stream) {
  const float* x   = (const float*)d_in[0];
  const float* wq  = (const float*)d_in[1];
  const float* bq  = (const float*)d_in[2];
  const float* wk  = (const float*)d_in[3];
  const float* bk  = (const float*)d_in[4];
  const float* wv  = (const float*)d_in[5];
  const float* bv  = (const float*)d_in[6];
  const float* wp  = (const float*)d_in[7];
  const float* bp  = (const float*)d_in[8];
  const float* gns = (const float*)d_in[9];
  const float* gnb = (const float*)d_in[10];
  float* out = (float*)d_out;

  const size_t MB = 1ull << 20;
  const size_t KB = 1024;
  char* wsb = (char*)d_ws;
  bf16*   WT     = (bf16*)(wsb);                       // 2 MB
  bf16*   wvb    = (bf16*)(wsb + 2 * MB);              // 512 KB
  float2* stats  = (float2*)(wsb + 2 * MB + 512 * KB);
  float*  s      = (float*)(wsb + 2 * MB + 576 * KB);
  float*  uq     = (float*)(wsb + 2 * MB + 640 * KB);
  float*  vkv    = (float*)(wsb + 2 * MB + 704 * KB);
  float*  attnbv = (float*)(wsb + 2 * MB + 832 * KB);  // 16 KB
  bf16*   HnT    = (bf16*)(wsb + 35 * MB);             // 32 MB
  float*  part   = (float*)(wsb + 67 * MB);            // 32 MB [4][8][512][512]
  bf16*   attnT  = (bf16*)(wsb + 67 * MB);             // overlay (part dead after gsumv)
  bf16*   T      = (bf16*)(wsb + 71 * MB);
  bf16*   CT     = (bf16*)(wsb + 75 * MB);
  bf16*   G      = (bf16*)(wsb + 99 * MB);             // 4 MB
  bf16*   M1     = (bf16*)(wsb + 103 * MB);            // 4 MB
  float*  L      = (float*)(wsb + 107 * MB);           // 8 MB

  const long S2 = 512 * 512;

  k_prep      <<<dim3(1280),    dim3(256), 0, stream>>>(x, wq, wk, wv, wp, WT, wvb, s, stats);
  k_gnapply_t <<<dim3(512),     dim3(256), 0, stream>>>(x, stats, gns, gnb, HnT, s);
  k_gram      <<<dim3(320),     dim3(256), 0, stream>>>(HnT, part);
  k_gsumv     <<<dim3(2064),    dim3(256), 0, stream>>>(part, G, WT, s, uq, vkv);
  k_sg64_bf   <<<dim3(8, 8, 8), dim3(256), 0, stream>>>(WT, 0, G, S2, M1);
  k_sg64_f32  <<<dim3(8, 8, 8), dim3(256), 0, stream>>>(M1, S2, WT + (size_t)512 * 512, 0, L);
  k_smax      <<<dim3(1024),    dim3(256), 0, stream>>>(L, uq, vkv, bq, bk, bv, attnT, attnbv);
  k_sg64_bf   <<<dim3(8, 8, 8), dim3(256), 0, stream>>>(WT + (size_t)3 * 512 * 512, 0, attnT, S2, T);
  k_sg64_bf   <<<dim3(8, 8, 8), dim3(256), 0, stream>>>(T, S2, wvb, 0, CT);
  k_final     <<<dim3(1024),    dim3(256), 0, stream>>>(x, CT, attnbv, WT + (size_t)3 * 512 * 512,
                                                        gns, gnb, stats, bp, x == nullptr ? nullptr : out);
}

// Round 8
// 191.029 us; speedup vs baseline: 1.4568x; 1.0063x over previous
//
#include <hip/hip_runtime.h>
#include <hip/hip_bf16.h>

// SelfAttention (channel attention) on MI355X. Inputs fp32, OUTPUT fp32.
//   Hn = GN(x) (bf16, row-major + transposed HnT)
//   G_b = Hn_b^T Hn_b ; L_b = Wq^T G_b Wk + rank-1 bias terms
//   attn_b = softmax_rows(L_b) ; attnbv[k] = attn_b[k,:]·bv
//   CT_b = (Wp^T attn_b) Wv^T ; dv = Wp^T attnbv
//   out = x + Hn CT_b^T + dv + bp
// gemm(A,B): C[m][n] = sum_k A[m][k]*B[n][k] (both K-contiguous).
// R8: revert R7's inline-GN-in-final (VALU on staging critical path starved
//     MFMA: 10.5% util, 60 us). Hn materialized bf16 again; k_final stages
//     pure bf16x8. Keep: 10-dispatch fusion, dv-in-final, XCD-compact grids,
//     LDS XOR-swizzle, symmetric gram.
// Workspace:
//   [0,2)MB WT[2048][512]bf16 ; [2,2.5) wvb ; 2.5MB stats ; +64K s ; +128K uq ;
//   +192K vkv ; +832K attnbv[8][512]f32
//   [3,35)  Hn [8*4096][512] bf16
//   [35,67) HnT [8][512][4096] bf16
//   [67,99) part [4][8][512][512] f32 -> later attnT(67) T(71) CT(75)
//   [99,103) G ; [103,107) M1 ; [107,115) L f32

using bf16   = __bf16;
using bf16x8 = __attribute__((ext_vector_type(8))) __bf16;
using bf16x4 = __attribute__((ext_vector_type(4))) __bf16;
using f32x4  = __attribute__((ext_vector_type(4))) float;

#define DI __device__ __forceinline__

// ---------------- 128x128 tile core, LDS XOR-swizzled ----------------
DI void gemm128_core(const bf16* __restrict__ A, long lda,
                     const bf16* __restrict__ B, long ldb,
                     int ksteps, bf16* As, bf16* Bs, f32x4 acc[4][4]) {
  const int tid  = threadIdx.x;
  const int lane = tid & 63;
  const int w    = tid >> 6;
  const int lr   = lane & 15;
  const int lk   = (lane >> 4) * 8;
  const int wr   = (w >> 1) * 64;
  const int wc   = (w & 1) * 64;
  const int sw   = (lr & 7) << 3;

  for (int kt = 0; kt < ksteps; ++kt) {
    bf16x8 av[4], bv[4];
#pragma unroll
    for (int c = 0; c < 4; ++c) {
      const int idx = c * 256 + tid;
      const int row = idx >> 3, col = (idx & 7) * 8;
      av[c] = *(const bf16x8*)(A + (long)row * lda + (long)kt * 64 + col);
      bv[c] = *(const bf16x8*)(B + (long)row * ldb + (long)kt * 64 + col);
    }
#pragma unroll
    for (int c = 0; c < 4; ++c) {
      const int idx = c * 256 + tid;
      const int row = idx >> 3;
      const int scol = ((idx & 7) * 8) ^ ((row & 7) << 3);
      *(bf16x8*)(As + row * 64 + scol) = av[c];
      *(bf16x8*)(Bs + row * 64 + scol) = bv[c];
    }
    __syncthreads();
#pragma unroll
    for (int kk = 0; kk < 2; ++kk) {
      bf16x8 af[4], bfr[4];
#pragma unroll
      for (int i = 0; i < 4; ++i)
        af[i] = *(const bf16x8*)(As + (wr + i * 16 + lr) * 64 + ((kk * 32 + lk) ^ sw));
#pragma unroll
      for (int i = 0; i < 4; ++i)
        bfr[i] = *(const bf16x8*)(Bs + (wc + i * 16 + lr) * 64 + ((kk * 32 + lk) ^ sw));
#pragma unroll
      for (int i = 0; i < 4; ++i)
#pragma unroll
        for (int j = 0; j < 4; ++j)
          acc[i][j] = __builtin_amdgcn_mfma_f32_16x16x32_bf16(af[i], bfr[j], acc[i][j], 0, 0, 0);
    }
    __syncthreads();
  }
}

// ---------------- 64x64 tile core, LDS XOR-swizzled ----------------
DI void gemm64_core(const bf16* __restrict__ A, long lda,
                    const bf16* __restrict__ B, long ldb,
                    int ksteps, bf16* As, bf16* Bs, f32x4 acc[2][2]) {
  const int tid  = threadIdx.x;
  const int lane = tid & 63;
  const int w    = tid >> 6;
  const int lr   = lane & 15;
  const int lk   = (lane >> 4) * 8;
  const int wr   = (w >> 1) * 32;
  const int wc   = (w & 1) * 32;
  const int sw   = (lr & 7) << 3;

  for (int kt = 0; kt < ksteps; ++kt) {
    bf16x8 av[2], bv[2];
#pragma unroll
    for (int c = 0; c < 2; ++c) {
      const int idx = c * 256 + tid;
      const int row = idx >> 3, col = (idx & 7) * 8;
      av[c] = *(const bf16x8*)(A + (long)row * lda + (long)kt * 64 + col);
      bv[c] = *(const bf16x8*)(B + (long)row * ldb + (long)kt * 64 + col);
    }
#pragma unroll
    for (int c = 0; c < 2; ++c) {
      const int idx = c * 256 + tid;
      const int row = idx >> 3;
      const int scol = ((idx & 7) * 8) ^ ((row & 7) << 3);
      *(bf16x8*)(As + row * 64 + scol) = av[c];
      *(bf16x8*)(Bs + row * 64 + scol) = bv[c];
    }
    __syncthreads();
#pragma unroll
    for (int kk = 0; kk < 2; ++kk) {
      bf16x8 af[2], bfr[2];
#pragma unroll
      for (int i = 0; i < 2; ++i)
        af[i] = *(const bf16x8*)(As + (wr + i * 16 + lr) * 64 + ((kk * 32 + lk) ^ sw));
#pragma unroll
      for (int i = 0; i < 2; ++i)
        bfr[i] = *(const bf16x8*)(Bs + (wc + i * 16 + lr) * 64 + ((kk * 32 + lk) ^ sw));
#pragma unroll
      for (int i = 0; i < 2; ++i)
#pragma unroll
        for (int j = 0; j < 2; ++j)
          acc[i][j] = __builtin_amdgcn_mfma_f32_16x16x32_bf16(af[i], bfr[j], acc[i][j], 0, 0, 0);
    }
    __syncthreads();
  }
}

// ---------------- prep: GN stats (blocks 0..255) + weight transpose (256..1279) ----------------
__global__ __launch_bounds__(256) void k_prep(const float* __restrict__ x,
                                              const float* __restrict__ wq,
                                              const float* __restrict__ wk,
                                              const float* __restrict__ wv,
                                              const float* __restrict__ wp,
                                              bf16* __restrict__ WT,
                                              bf16* __restrict__ wvb,
                                              float* __restrict__ s,
                                              float2* __restrict__ stats) {
  __shared__ float shm[1056];
  const int tid = threadIdx.x;
  const int bx = blockIdx.x;
  if (bx < 256) {
    const int b = bx >> 5, g = bx & 31;
    const float* base = x + (size_t)b * 4096 * 512 + g * 16;
    float sm = 0.f, ss = 0.f;
    for (int it = 0; it < 64; ++it) {
      const int idx = it * 256 + tid;
      const int p = idx >> 2, c4 = (idx & 3) * 4;
      float4 v = *(const float4*)(base + (size_t)p * 512 + c4);
      sm += v.x + v.y + v.z + v.w;
      ss += v.x * v.x + v.y * v.y + v.z * v.z + v.w * v.w;
    }
    float* rs = shm; float* rss = shm + 256;
    rs[tid] = sm; rss[tid] = ss; __syncthreads();
    for (int off = 128; off; off >>= 1) {
      if (tid < off) { rs[tid] += rs[tid + off]; rss[tid] += rss[tid + off]; }
      __syncthreads();
    }
    if (tid == 0) {
      float mean = rs[0] * (1.f / 65536.f);
      float var  = rss[0] * (1.f / 65536.f) - mean * mean;
      stats[bx] = float2{mean, rsqrtf(var + 1e-5f)};
    }
  } else {
    const int r = bx - 256;             // 0..1023
    const int z = r >> 8;
    const int r2 = r & 255;
    const int bxx = r2 & 15, byy = r2 >> 4;
    const int tx = tid & 31, ty = tid >> 5;
    const float* src = (z == 0) ? wq : (z == 1) ? wk : (z == 2) ? wv : wp;
    const int n0 = bxx * 32, k0 = byy * 32;
    if (z == 0 && byy == 0) s[bxx * 256 + tid] = 0.f;
#pragma unroll
    for (int j = 0; j < 4; ++j) {
      const float v = src[(size_t)(k0 + ty + j * 8) * 512 + n0 + tx];
      shm[(ty + j * 8) * 33 + tx] = v;
      if (z == 2) wvb[(size_t)(k0 + ty + j * 8) * 512 + n0 + tx] = (bf16)v;
    }
    __syncthreads();
#pragma unroll
    for (int j = 0; j < 4; ++j)
      WT[(size_t)(z * 512 + n0 + ty + j * 8) * 512 + k0 + tx] = (bf16)shm[tx * 33 + ty + j * 8];
  }
}

// ---------------- GN apply -> Hn + HnT + col-sums s ----------------
__global__ __launch_bounds__(256) void k_gnapply_t(const float* __restrict__ x,
                                                   const float2* __restrict__ stats,
                                                   const float* __restrict__ gns,
                                                   const float* __restrict__ gnb,
                                                   bf16* __restrict__ Hn,
                                                   bf16* __restrict__ HnT,
                                                   float* __restrict__ s) {
  __shared__ bf16 tile[64 * 516];
  __shared__ float cs[512];
  const int tid = threadIdx.x;
  const int blk = blockIdx.x;       // 0..511
  const int b = blk >> 6, p0 = (blk & 63) * 64;
  cs[tid] = 0.f; cs[tid + 256] = 0.f;
  __syncthreads();

  const int c4 = (tid & 127) * 4;
  const int hi = tid >> 7;
  const float2 st = stats[b * 32 + (c4 >> 4)];
  const float4 sc = *(const float4*)(gns + c4);
  const float4 bi = *(const float4*)(gnb + c4);
  float a0 = 0.f, a1 = 0.f, a2 = 0.f, a3 = 0.f;
  for (int i = 0; i < 32; ++i) {
    const int px = i * 2 + hi;
    const float4 xv = *(const float4*)(x + ((size_t)(b * 4096 + p0 + px)) * 512 + c4);
    const float h0 = (xv.x - st.x) * st.y * sc.x + bi.x;
    const float h1 = (xv.y - st.x) * st.y * sc.y + bi.y;
    const float h2 = (xv.z - st.x) * st.y * sc.z + bi.z;
    const float h3 = (xv.w - st.x) * st.y * sc.w + bi.w;
    a0 += h0; a1 += h1; a2 += h2; a3 += h3;
    bf16x4 hv;
    hv[0] = (bf16)h0; hv[1] = (bf16)h1; hv[2] = (bf16)h2; hv[3] = (bf16)h3;
    *(bf16x4*)(Hn + ((size_t)(b * 4096 + p0 + px)) * 512 + c4) = hv;
    *(bf16x4*)(tile + px * 516 + c4) = hv;
  }
  atomicAdd(&cs[c4 + 0], a0); atomicAdd(&cs[c4 + 1], a1);
  atomicAdd(&cs[c4 + 2], a2); atomicAdd(&cs[c4 + 3], a3);
  __syncthreads();
  atomicAdd(s + b * 512 + tid, cs[tid]);
  atomicAdd(s + b * 512 + 256 + tid, cs[tid + 256]);

  for (int cg = 0; cg < 16; ++cg) {
    const int c  = cg * 32 + (tid >> 3);
    const int so = (tid & 7) * 8;
    bf16x8 pk;
#pragma unroll
    for (int k = 0; k < 8; ++k) pk[k] = tile[(so + k) * 516 + c];
    *(bf16x8*)(HnT + ((size_t)(b * 512 + c)) * 4096 + p0 + so) = pk;
  }
}

// ---------------- Gram: symmetric tiles, split-K=4, xcd==batch ----------------
__global__ __launch_bounds__(256) void k_gram(const bf16* __restrict__ HnT,
                                              float* __restrict__ part) {
  __shared__ bf16 As[128 * 64], Bs[128 * 64];
  const int Lb = blockIdx.x;           // 0..319 ; xcd = Lb%8 = batch
  const int b  = Lb & 7;
  const int idx = Lb >> 3;             // 0..39
  const int sp = idx & 3;
  const int t  = idx >> 2;             // 0..9 upper-tri tile id
  const int m0 = (int)((0x3221110000ull >> (4 * t)) & 15) * 128;
  const int n0 = (int)((0x3323213210ull >> (4 * t)) & 15) * 128;
  f32x4 acc[4][4];
#pragma unroll
  for (int i = 0; i < 4; ++i)
#pragma unroll
    for (int j = 0; j < 4; ++j) acc[i][j] = (f32x4){0.f, 0.f, 0.f, 0.f};
  const bf16* A = HnT + ((size_t)b * 512 + m0) * 4096 + sp * 1024;
  const bf16* B = HnT + ((size_t)b * 512 + n0) * 4096 + sp * 1024;
  gemm128_core(A, 4096, B, 4096, 16, As, Bs, acc);

  const int lane = threadIdx.x & 63, w = threadIdx.x >> 6;
  const int wr = (w >> 1) * 64, wc = (w & 1) * 64;
  const int rr = (lane >> 4) * 4, cc = lane & 15;
  float* dst = part + (size_t)(sp * 8 + b) * 262144;
#pragma unroll
  for (int i = 0; i < 4; ++i) {
#pragma unroll
    for (int j = 0; j < 4; ++j) {
      const int gm = m0 + wr + i * 16 + rr;
      const int gn = n0 + wc + j * 16 + cc;
      float* p = dst + (size_t)gm * 512 + gn;
      p[0]    = acc[i][j][0];
      p[512]  = acc[i][j][1];
      p[1024] = acc[i][j][2];
      p[1536] = acc[i][j][3];
      if (m0 != n0)
        *(f32x4*)(dst + (size_t)gn * 512 + gm) = acc[i][j];
    }
  }
}

// ---------------- gsum (blocks 0..2047) + uq/vkv small gemv (2048..2063) ----------------
__global__ __launch_bounds__(256) void k_gsumv(const float* __restrict__ part,
                                               bf16* __restrict__ G,
                                               const bf16* __restrict__ WT,
                                               const float* __restrict__ s,
                                               float* __restrict__ uq,
                                               float* __restrict__ vkv) {
  const int bx = blockIdx.x, tid = threadIdx.x;
  if (bx < 2048) {
    const size_t S8 = (size_t)8 * 262144;
    const size_t i4 = ((size_t)bx * 256 + tid) * 4;
    const float4 a = *(const float4*)(part + i4);
    const float4 c = *(const float4*)(part + i4 + S8);
    const float4 d = *(const float4*)(part + i4 + 2 * S8);
    const float4 e = *(const float4*)(part + i4 + 3 * S8);
    bf16x4 o;
    o[0] = (bf16)(a.x + c.x + d.x + e.x); o[1] = (bf16)(a.y + c.y + d.y + e.y);
    o[2] = (bf16)(a.z + c.z + d.z + e.z); o[3] = (bf16)(a.w + c.w + d.w + e.w);
    *(bf16x4*)(G + i4) = o;
  } else {
    const int z = bx - 2048;            // 0..15
    const int which = z >> 3, b = z & 7;
    const float* sv = s + b * 512;
    for (int o = tid; o < 512; o += 256) {
      const bf16* row = WT + ((size_t)(which * 512 + o)) * 512;
      float acc = 0.f;
      for (int c = 0; c < 512; c += 8) {
        bf16x8 v = *(const bf16x8*)(row + c);
        const float4 s0 = *(const float4*)(sv + c);
        const float4 s1 = *(const float4*)(sv + c + 4);
        acc += (float)v[0] * s0.x + (float)v[1] * s0.y + (float)v[2] * s0.z +
               (float)v[3] * s0.w + (float)v[4] * s1.x + (float)v[5] * s1.y +
               (float)v[6] * s1.z + (float)v[7] * s1.w;
      }
      (which == 0 ? uq : vkv)[b * 512 + o] = acc;
    }
  }
}

// ---------------- batched small GEMM 512x512x512, bf16 out ----------------
__global__ __launch_bounds__(256) void k_sg64_bf(const bf16* __restrict__ Ab, long a_bs,
                                                 const bf16* __restrict__ Bb, long b_bs,
                                                 bf16* __restrict__ Cb) {
  __shared__ bf16 As[64 * 64], Bs[64 * 64];
  const int b = blockIdx.z;
  const int m0 = blockIdx.y * 64, n0 = blockIdx.x * 64;
  f32x4 acc[2][2];
#pragma unroll
  for (int i = 0; i < 2; ++i)
#pragma unroll
    for (int j = 0; j < 2; ++j) acc[i][j] = (f32x4){0.f, 0.f, 0.f, 0.f};
  gemm64_core(Ab + (size_t)b * a_bs + (size_t)m0 * 512, 512,
              Bb + (size_t)b * b_bs + (size_t)n0 * 512, 512, 8, As, Bs, acc);

  const int lane = threadIdx.x & 63, w = threadIdx.x >> 6;
  const int wr = (w >> 1) * 32, wc = (w & 1) * 32;
  const int rr = (lane >> 4) * 4, cc = lane & 15;
  bf16* dst = Cb + (size_t)b * 262144;
#pragma unroll
  for (int i = 0; i < 2; ++i) {
#pragma unroll
    for (int j = 0; j < 2; ++j) {
      const int gm = m0 + wr + i * 16 + rr;
      const int gn = n0 + wc + j * 16 + cc;
      bf16* p = dst + (size_t)gm * 512 + gn;
      p[0]    = (bf16)acc[i][j][0];
      p[512]  = (bf16)acc[i][j][1];
      p[1024] = (bf16)acc[i][j][2];
      p[1536] = (bf16)acc[i][j][3];
    }
  }
}

// ---------------- batched small GEMM 512x512x512, fp32 out ----------------
__global__ __launch_bounds__(256) void k_sg64_f32(const bf16* __restrict__ Ab, long a_bs,
                                                  const bf16* __restrict__ Bb, long b_bs,
                                                  float* __restrict__ Cb) {
  __shared__ bf16 As[64 * 64], Bs[64 * 64];
  const int b = blockIdx.z;
  const int m0 = blockIdx.y * 64, n0 = blockIdx.x * 64;
  f32x4 acc[2][2];
#pragma unroll
  for (int i = 0; i < 2; ++i)
#pragma unroll
    for (int j = 0; j < 2; ++j) acc[i][j] = (f32x4){0.f, 0.f, 0.f, 0.f};
  gemm64_core(Ab + (size_t)b * a_bs + (size_t)m0 * 512, 512,
              Bb + (size_t)b * b_bs + (size_t)n0 * 512, 512, 8, As, Bs, acc);

  const int lane = threadIdx.x & 63, w = threadIdx.x >> 6;
  const int wr = (w >> 1) * 32, wc = (w & 1) * 32;
  const int rr = (lane >> 4) * 4, cc = lane & 15;
  float* dst = Cb + (size_t)b * 262144;
#pragma unroll
  for (int i = 0; i < 2; ++i) {
#pragma unroll
    for (int j = 0; j < 2; ++j) {
      const int gm = m0 + wr + i * 16 + rr;
      const int gn = n0 + wc + j * 16 + cc;
      float* p = dst + (size_t)gm * 512 + gn;
      p[0]    = acc[i][j][0];
      p[512]  = acc[i][j][1];
      p[1024] = acc[i][j][2];
      p[1536] = acc[i][j][3];
    }
  }
}

// ---------------- softmax (4 rows/block, wave-shuffle) -> attnT + attnbv ----------------
__global__ __launch_bounds__(256) void k_smax(const float* __restrict__ L,
                                              const float* __restrict__ uq,
                                              const float* __restrict__ vkv,
                                              const float* __restrict__ bq,
                                              const float* __restrict__ bk,
                                              const float* __restrict__ bv,
                                              bf16* __restrict__ attnT,
                                              float* __restrict__ attnbv) {
  __shared__ bf16 p[4][512];
  const int tid = threadIdx.x;
  const int w = tid >> 6, l = tid & 63;
  const int blk = blockIdx.x;          // 0..1023, 4 rows each
  const int gr = blk * 4 + w;          // global row
  const int b = gr >> 9, i = gr & 511;
  const int c = l * 8;

  const float r  = uq[b * 512 + i];
  const float q0 = bq[i];
  const float* lp = L + (size_t)gr * 512 + c;
  const float4 l0 = *(const float4*)lp;
  const float4 l1 = *(const float4*)(lp + 4);
  const float4 k0 = *(const float4*)(bk + c);
  const float4 k1 = *(const float4*)(bk + c + 4);
  const float4 g0 = *(const float4*)(vkv + b * 512 + c);
  const float4 g1 = *(const float4*)(vkv + b * 512 + c + 4);
  float v[8];
  v[0] = l0.x + r * k0.x + q0 * (g0.x + 4096.f * k0.x);
  v[1] = l0.y + r * k0.y + q0 * (g0.y + 4096.f * k0.y);
  v[2] = l0.z + r * k0.z + q0 * (g0.z + 4096.f * k0.z);
  v[3] = l0.w + r * k0.w + q0 * (g0.w + 4096.f * k0.w);
  v[4] = l1.x + r * k1.x + q0 * (g1.x + 4096.f * k1.x);
  v[5] = l1.y + r * k1.y + q0 * (g1.y + 4096.f * k1.y);
  v[6] = l1.z + r * k1.z + q0 * (g1.z + 4096.f * k1.z);
  v[7] = l1.w + r * k1.w + q0 * (g1.w + 4096.f * k1.w);

  float mx = v[0];
#pragma unroll
  for (int j = 1; j < 8; ++j) mx = fmaxf(mx, v[j]);
  for (int off = 32; off; off >>= 1) mx = fmaxf(mx, __shfl_xor(mx, off));
  float e[8], sm = 0.f;
#pragma unroll
  for (int j = 0; j < 8; ++j) { e[j] = __expf(v[j] - mx); sm += e[j]; }
  for (int off = 32; off; off >>= 1) sm += __shfl_xor(sm, off);
  const float inv = 1.f / sm;

  const float4 b0 = *(const float4*)(bv + c);
  const float4 b1 = *(const float4*)(bv + c + 4);
  float ab = e[0] * b0.x + e[1] * b0.y + e[2] * b0.z + e[3] * b0.w +
             e[4] * b1.x + e[5] * b1.y + e[6] * b1.z + e[7] * b1.w;
  ab *= inv;
  for (int off = 32; off; off >>= 1) ab += __shfl_xor(ab, off);
  if (l == 0) attnbv[gr] = ab;

  bf16x8 o;
#pragma unroll
  for (int j = 0; j < 8; ++j) o[j] = (bf16)(e[j] * inv);
  *(bf16x8*)(&p[w][c]) = o;
  __syncthreads();

  const int i0 = (blk * 4) & 511;
  for (int n = tid; n < 512; n += 256) {
    bf16x4 t;
    t[0] = p[0][n]; t[1] = p[1][n]; t[2] = p[2][n]; t[3] = p[3][n];
    *(bf16x4*)(attnT + (size_t)b * 262144 + (size_t)n * 512 + i0) = t;
  }
}

// ---------------- final: out = x + Hn CT^T + dv + bp ; xcd==batch grid ----------------
__global__ __launch_bounds__(256) void k_final(const bf16* __restrict__ Hn,
                                               const bf16* __restrict__ CT,
                                               const float* __restrict__ attnbv,
                                               const bf16* __restrict__ WTp,
                                               const float* __restrict__ bp,
                                               const float* __restrict__ x,
                                               float* __restrict__ out) {
  __shared__ bf16 As[128 * 64], Bs[128 * 64];
  __shared__ float abvs[512], dvs[128];
  const int Lb = blockIdx.x;           // 0..1023 ; xcd = Lb%8 = batch
  const int b  = Lb & 7;
  const int idx = Lb >> 3;
  const int m0 = (idx >> 2) * 128;
  const int n0 = (idx & 3) * 128;
  const int tid = threadIdx.x;

  for (int cch = tid; cch < 512; cch += 256)
    abvs[cch] = attnbv[b * 512 + cch];
  __syncthreads();
  if (tid < 128) {                     // dv for columns n0..n0+127
    const bf16* wrow = WTp + (size_t)(n0 + tid) * 512;
    float acc = 0.f;
    for (int k = 0; k < 512; k += 8) {
      bf16x8 v = *(const bf16x8*)(wrow + k);
#pragma unroll
      for (int j = 0; j < 8; ++j) acc += (float)v[j] * abvs[k + j];
    }
    dvs[tid] = acc;
  }

  f32x4 acc[4][4];
#pragma unroll
  for (int i = 0; i < 4; ++i)
#pragma unroll
    for (int j = 0; j < 4; ++j) acc[i][j] = (f32x4){0.f, 0.f, 0.f, 0.f};
  gemm128_core(Hn + ((size_t)(b * 4096 + m0)) * 512, 512,
               CT + (size_t)b * 262144 + (size_t)n0 * 512, 512, 8, As, Bs, acc);

  const int lane = tid & 63, w = tid >> 6;
  const int wr = (w >> 1) * 64, wc = (w & 1) * 64;
  const int rr = (lane >> 4) * 4, cc = lane & 15;
#pragma unroll
  for (int i = 0; i < 4; ++i) {
#pragma unroll
    for (int j = 0; j < 4; ++j) {
      const int gm = m0 + wr + i * 16 + rr;
      const int gn = n0 + wc + j * 16 + cc;
      const float add = dvs[gn - n0] + bp[gn];
#pragma unroll
      for (int jj = 0; jj < 4; ++jj) {
        const size_t off = ((size_t)(b * 4096 + gm + jj)) * 512 + gn;
        out[off] = acc[i][j][jj] + add + x[off];
      }
    }
  }
}

extern "C" void kernel_launch(void* const* d_in, const int* in_sizes, int n_in,
                              void* d_out, int out_size, void* d_ws, size_t ws_size,
                              hipStream_t stream) {
  const float* x   = (const float*)d_in[0];
  const float* wq  = (const float*)d_in[1];
  const float* bq  = (const float*)d_in[2];
  const float* wk  = (const float*)d_in[3];
  const float* bk  = (const float*)d_in[4];
  const float* wv  = (const float*)d_in[5];
  const float* bv  = (const float*)d_in[6];
  const float* wp  = (const float*)d_in[7];
  const float* bp  = (const float*)d_in[8];
  const float* gns = (const float*)d_in[9];
  const float* gnb = (const float*)d_in[10];
  float* out = (float*)d_out;

  const size_t MB = 1ull << 20;
  const size_t KB = 1024;
  char* wsb = (char*)d_ws;
  bf16*   WT     = (bf16*)(wsb);                       // 2 MB
  bf16*   wvb    = (bf16*)(wsb + 2 * MB);              // 512 KB
  float2* stats  = (float2*)(wsb + 2 * MB + 512 * KB);
  float*  s      = (float*)(wsb + 2 * MB + 576 * KB);
  float*  uq     = (float*)(wsb + 2 * MB + 640 * KB);
  float*  vkv    = (float*)(wsb + 2 * MB + 704 * KB);
  float*  attnbv = (float*)(wsb + 2 * MB + 832 * KB);  // 16 KB
  bf16*   Hn     = (bf16*)(wsb + 3 * MB);              // 32 MB
  bf16*   HnT    = (bf16*)(wsb + 35 * MB);             // 32 MB
  float*  part   = (float*)(wsb + 67 * MB);            // 32 MB [4][8][512][512]
  bf16*   attnT  = (bf16*)(wsb + 67 * MB);             // overlay (part dead after gsumv)
  bf16*   T      = (bf16*)(wsb + 71 * MB);
  bf16*   CT     = (bf16*)(wsb + 75 * MB);
  bf16*   G      = (bf16*)(wsb + 99 * MB);             // 4 MB
  bf16*   M1     = (bf16*)(wsb + 103 * MB);            // 4 MB
  float*  L      = (float*)(wsb + 107 * MB);           // 8 MB

  const long S2 = 512 * 512;

  k_prep      <<<dim3(1280),    dim3(256), 0, stream>>>(x, wq, wk, wv, wp, WT, wvb, s, stats);
  k_gnapply_t <<<dim3(512),     dim3(256), 0, stream>>>(x, stats, gns, gnb, Hn, HnT, s);
  k_gram      <<<dim3(320),     dim3(256), 0, stream>>>(HnT, part);
  k_gsumv     <<<dim3(2064),    dim3(256), 0, stream>>>(part, G, WT, s, uq, vkv);
  k_sg64_bf   <<<dim3(8, 8, 8), dim3(256), 0, stream>>>(WT, 0, G, S2, M1);
  k_sg64_f32  <<<dim3(8, 8, 8), dim3(256), 0, stream>>>(M1, S2, WT + (size_t)512 * 512, 0, L);
  k_smax      <<<dim3(1024),    dim3(256), 0, stream>>>(L, uq, vkv, bq, bk, bv, attnT, attnbv);
  k_sg64_bf   <<<dim3(8, 8, 8), dim3(256), 0, stream>>>(WT + (size_t)3 * 512 * 512, 0, attnT, S2, T);
  k_sg64_bf   <<<dim3(8, 8, 8), dim3(256), 0, stream>>>(T, S2, wvb, 0, CT);
  k_final     <<<dim3(1024),    dim3(256), 0, stream>>>(Hn, CT, attnbv, WT + (size_t)3 * 512 * 512,
                                                        bp, x, out);
}

// Round 9
// 183.516 us; speedup vs baseline: 1.5164x; 1.0409x over previous
//
#include <hip/hip_runtime.h>
#include <hip/hip_bf16.h>

// SelfAttention (channel attention) on MI355X. Inputs fp32, OUTPUT fp32.
//   Hn = GN(x) (bf16, row-major + transposed HnT)
//   G_b = Hn_b^T Hn_b ; L_b = Wq^T G_b Wk + rank-1 bias terms
//   attn_b = softmax_rows(L_b) ; attnbv[k] = attn_b[k,:]·bv
//   CT_b = (Wp^T attn_b) Wv^T ; dv = Wp^T attnbv
//   out = x + Hn CT_b^T + dv + bp
// gemm(A,B): C[m][n] = sum_k A[m][k]*B[n][k] (both K-contiguous).
// R9: GEMM cores staged via global_load_lds width=16 (m201 pattern:
//     linear LDS dest + inverse-swizzled global source + swizzled ds_read).
//     R8's reg-staged 2-barrier loop was the k_final bottleneck (10% MfmaUtil).
// Workspace: unchanged from R8.

using bf16   = __bf16;
using bf16x8 = __attribute__((ext_vector_type(8))) __bf16;
using bf16x4 = __attribute__((ext_vector_type(4))) __bf16;
using f32x4  = __attribute__((ext_vector_type(4))) float;

#define DI __device__ __forceinline__

DI void gload16(const bf16* g, bf16* l) {
  __builtin_amdgcn_global_load_lds(
      (const __attribute__((address_space(1))) void*)g,
      (__attribute__((address_space(3))) void*)l, 16, 0, 0);
}

// ---------------- 128x128 tile core: gload_lds staging + XOR-swizzled reads ----
// LDS holds, at (row, col8): global (row, col8 ^ (row&7)).  Staged rows per
// chunk c: c*32 + w*8 + (lane>>3)  => row&7 == lane>>3, so the source lane
// pre-swizzle is ((lane&7)^(lane>>3))*8 and the LDS dest is linear.
DI void gemm128_core(const bf16* __restrict__ A, long lda,
                     const bf16* __restrict__ B, long ldb,
                     int ksteps, bf16* As, bf16* Bs, f32x4 acc[4][4]) {
  const int tid  = threadIdx.x;
  const int lane = tid & 63;
  const int w    = tid >> 6;
  const int lr   = lane & 15;
  const int lk   = (lane >> 4) * 8;
  const int wr   = (w >> 1) * 64;
  const int wc   = (w & 1) * 64;
  const int sw   = (lr & 7) << 3;

  const int  srow = lane >> 3;                       // 0..7
  const int  ssw  = ((lane & 7) ^ srow) << 3;        // pre-swizzled col
  const bf16* ga = A + (long)(w * 8 + srow) * lda + ssw;
  const bf16* gb = B + (long)(w * 8 + srow) * ldb + ssw;
  bf16* lA = As + w * 512;                           // wave-uniform LDS base
  bf16* lB = Bs + w * 512;

  for (int kt = 0; kt < ksteps; ++kt) {
#pragma unroll
    for (int c = 0; c < 4; ++c) {
      gload16(ga + (long)c * 32 * lda, lA + c * 2048);
      gload16(gb + (long)c * 32 * ldb, lB + c * 2048);
    }
    ga += 64; gb += 64;
    __syncthreads();                                 // drains vmcnt: tile ready
#pragma unroll
    for (int kk = 0; kk < 2; ++kk) {
      bf16x8 af[4], bfr[4];
#pragma unroll
      for (int i = 0; i < 4; ++i)
        af[i] = *(const bf16x8*)(As + (wr + i * 16 + lr) * 64 + ((kk * 32 + lk) ^ sw));
#pragma unroll
      for (int i = 0; i < 4; ++i)
        bfr[i] = *(const bf16x8*)(Bs + (wc + i * 16 + lr) * 64 + ((kk * 32 + lk) ^ sw));
#pragma unroll
      for (int i = 0; i < 4; ++i)
#pragma unroll
        for (int j = 0; j < 4; ++j)
          acc[i][j] = __builtin_amdgcn_mfma_f32_16x16x32_bf16(af[i], bfr[j], acc[i][j], 0, 0, 0);
    }
    __syncthreads();                                 // protect LDS for next kt
  }
}

// ---------------- 64x64 tile core: same staging pattern ----------------
DI void gemm64_core(const bf16* __restrict__ A, long lda,
                    const bf16* __restrict__ B, long ldb,
                    int ksteps, bf16* As, bf16* Bs, f32x4 acc[2][2]) {
  const int tid  = threadIdx.x;
  const int lane = tid & 63;
  const int w    = tid >> 6;
  const int lr   = lane & 15;
  const int lk   = (lane >> 4) * 8;
  const int wr   = (w >> 1) * 32;
  const int wc   = (w & 1) * 32;
  const int sw   = (lr & 7) << 3;

  const int  srow = lane >> 3;
  const int  ssw  = ((lane & 7) ^ srow) << 3;
  const bf16* ga = A + (long)(w * 8 + srow) * lda + ssw;
  const bf16* gb = B + (long)(w * 8 + srow) * ldb + ssw;
  bf16* lA = As + w * 512;
  bf16* lB = Bs + w * 512;

  for (int kt = 0; kt < ksteps; ++kt) {
#pragma unroll
    for (int c = 0; c < 2; ++c) {
      gload16(ga + (long)c * 32 * lda, lA + c * 2048);
      gload16(gb + (long)c * 32 * ldb, lB + c * 2048);
    }
    ga += 64; gb += 64;
    __syncthreads();
#pragma unroll
    for (int kk = 0; kk < 2; ++kk) {
      bf16x8 af[2], bfr[2];
#pragma unroll
      for (int i = 0; i < 2; ++i)
        af[i] = *(const bf16x8*)(As + (wr + i * 16 + lr) * 64 + ((kk * 32 + lk) ^ sw));
#pragma unroll
      for (int i = 0; i < 2; ++i)
        bfr[i] = *(const bf16x8*)(Bs + (wc + i * 16 + lr) * 64 + ((kk * 32 + lk) ^ sw));
#pragma unroll
      for (int i = 0; i < 2; ++i)
#pragma unroll
        for (int j = 0; j < 2; ++j)
          acc[i][j] = __builtin_amdgcn_mfma_f32_16x16x32_bf16(af[i], bfr[j], acc[i][j], 0, 0, 0);
    }
    __syncthreads();
  }
}

// ---------------- prep: GN stats (blocks 0..255) + weight transpose (256..1279) ----------------
__global__ __launch_bounds__(256) void k_prep(const float* __restrict__ x,
                                              const float* __restrict__ wq,
                                              const float* __restrict__ wk,
                                              const float* __restrict__ wv,
                                              const float* __restrict__ wp,
                                              bf16* __restrict__ WT,
                                              bf16* __restrict__ wvb,
                                              float* __restrict__ s,
                                              float2* __restrict__ stats) {
  __shared__ float shm[1056];
  const int tid = threadIdx.x;
  const int bx = blockIdx.x;
  if (bx < 256) {
    const int b = bx >> 5, g = bx & 31;
    const float* base = x + (size_t)b * 4096 * 512 + g * 16;
    float sm = 0.f, ss = 0.f;
    for (int it = 0; it < 64; ++it) {
      const int idx = it * 256 + tid;
      const int p = idx >> 2, c4 = (idx & 3) * 4;
      float4 v = *(const float4*)(base + (size_t)p * 512 + c4);
      sm += v.x + v.y + v.z + v.w;
      ss += v.x * v.x + v.y * v.y + v.z * v.z + v.w * v.w;
    }
    float* rs = shm; float* rss = shm + 256;
    rs[tid] = sm; rss[tid] = ss; __syncthreads();
    for (int off = 128; off; off >>= 1) {
      if (tid < off) { rs[tid] += rs[tid + off]; rss[tid] += rss[tid + off]; }
      __syncthreads();
    }
    if (tid == 0) {
      float mean = rs[0] * (1.f / 65536.f);
      float var  = rss[0] * (1.f / 65536.f) - mean * mean;
      stats[bx] = float2{mean, rsqrtf(var + 1e-5f)};
    }
  } else {
    const int r = bx - 256;             // 0..1023
    const int z = r >> 8;
    const int r2 = r & 255;
    const int bxx = r2 & 15, byy = r2 >> 4;
    const int tx = tid & 31, ty = tid >> 5;
    const float* src = (z == 0) ? wq : (z == 1) ? wk : (z == 2) ? wv : wp;
    const int n0 = bxx * 32, k0 = byy * 32;
    if (z == 0 && byy == 0) s[bxx * 256 + tid] = 0.f;
#pragma unroll
    for (int j = 0; j < 4; ++j) {
      const float v = src[(size_t)(k0 + ty + j * 8) * 512 + n0 + tx];
      shm[(ty + j * 8) * 33 + tx] = v;
      if (z == 2) wvb[(size_t)(k0 + ty + j * 8) * 512 + n0 + tx] = (bf16)v;
    }
    __syncthreads();
#pragma unroll
    for (int j = 0; j < 4; ++j)
      WT[(size_t)(z * 512 + n0 + ty + j * 8) * 512 + k0 + tx] = (bf16)shm[tx * 33 + ty + j * 8];
  }
}

// ---------------- GN apply -> Hn + HnT + col-sums s ----------------
__global__ __launch_bounds__(256) void k_gnapply_t(const float* __restrict__ x,
                                                   const float2* __restrict__ stats,
                                                   const float* __restrict__ gns,
                                                   const float* __restrict__ gnb,
                                                   bf16* __restrict__ Hn,
                                                   bf16* __restrict__ HnT,
                                                   float* __restrict__ s) {
  __shared__ bf16 tile[64 * 516];
  __shared__ float cs[512];
  const int tid = threadIdx.x;
  const int blk = blockIdx.x;       // 0..511
  const int b = blk >> 6, p0 = (blk & 63) * 64;
  cs[tid] = 0.f; cs[tid + 256] = 0.f;
  __syncthreads();

  const int c4 = (tid & 127) * 4;
  const int hi = tid >> 7;
  const float2 st = stats[b * 32 + (c4 >> 4)];
  const float4 sc = *(const float4*)(gns + c4);
  const float4 bi = *(const float4*)(gnb + c4);
  float a0 = 0.f, a1 = 0.f, a2 = 0.f, a3 = 0.f;
  for (int i = 0; i < 32; ++i) {
    const int px = i * 2 + hi;
    const float4 xv = *(const float4*)(x + ((size_t)(b * 4096 + p0 + px)) * 512 + c4);
    const float h0 = (xv.x - st.x) * st.y * sc.x + bi.x;
    const float h1 = (xv.y - st.x) * st.y * sc.y + bi.y;
    const float h2 = (xv.z - st.x) * st.y * sc.z + bi.z;
    const float h3 = (xv.w - st.x) * st.y * sc.w + bi.w;
    a0 += h0; a1 += h1; a2 += h2; a3 += h3;
    bf16x4 hv;
    hv[0] = (bf16)h0; hv[1] = (bf16)h1; hv[2] = (bf16)h2; hv[3] = (bf16)h3;
    *(bf16x4*)(Hn + ((size_t)(b * 4096 + p0 + px)) * 512 + c4) = hv;
    *(bf16x4*)(tile + px * 516 + c4) = hv;
  }
  atomicAdd(&cs[c4 + 0], a0); atomicAdd(&cs[c4 + 1], a1);
  atomicAdd(&cs[c4 + 2], a2); atomicAdd(&cs[c4 + 3], a3);
  __syncthreads();
  atomicAdd(s + b * 512 + tid, cs[tid]);
  atomicAdd(s + b * 512 + 256 + tid, cs[tid + 256]);

  for (int cg = 0; cg < 16; ++cg) {
    const int c  = cg * 32 + (tid >> 3);
    const int so = (tid & 7) * 8;
    bf16x8 pk;
#pragma unroll
    for (int k = 0; k < 8; ++k) pk[k] = tile[(so + k) * 516 + c];
    *(bf16x8*)(HnT + ((size_t)(b * 512 + c)) * 4096 + p0 + so) = pk;
  }
}

// ---------------- Gram: symmetric tiles, split-K=4, xcd==batch ----------------
__global__ __launch_bounds__(256) void k_gram(const bf16* __restrict__ HnT,
                                              float* __restrict__ part) {
  __shared__ bf16 As[128 * 64], Bs[128 * 64];
  const int Lb = blockIdx.x;           // 0..319 ; xcd = Lb%8 = batch
  const int b  = Lb & 7;
  const int idx = Lb >> 3;             // 0..39
  const int sp = idx & 3;
  const int t  = idx >> 2;             // 0..9 upper-tri tile id
  const int m0 = (int)((0x3221110000ull >> (4 * t)) & 15) * 128;
  const int n0 = (int)((0x3323213210ull >> (4 * t)) & 15) * 128;
  f32x4 acc[4][4];
#pragma unroll
  for (int i = 0; i < 4; ++i)
#pragma unroll
    for (int j = 0; j < 4; ++j) acc[i][j] = (f32x4){0.f, 0.f, 0.f, 0.f};
  const bf16* A = HnT + ((size_t)b * 512 + m0) * 4096 + sp * 1024;
  const bf16* B = HnT + ((size_t)b * 512 + n0) * 4096 + sp * 1024;
  gemm128_core(A, 4096, B, 4096, 16, As, Bs, acc);

  const int lane = threadIdx.x & 63, w = threadIdx.x >> 6;
  const int wr = (w >> 1) * 64, wc = (w & 1) * 64;
  const int rr = (lane >> 4) * 4, cc = lane & 15;
  float* dst = part + (size_t)(sp * 8 + b) * 262144;
#pragma unroll
  for (int i = 0; i < 4; ++i) {
#pragma unroll
    for (int j = 0; j < 4; ++j) {
      const int gm = m0 + wr + i * 16 + rr;
      const int gn = n0 + wc + j * 16 + cc;
      float* p = dst + (size_t)gm * 512 + gn;
      p[0]    = acc[i][j][0];
      p[512]  = acc[i][j][1];
      p[1024] = acc[i][j][2];
      p[1536] = acc[i][j][3];
      if (m0 != n0)
        *(f32x4*)(dst + (size_t)gn * 512 + gm) = acc[i][j];
    }
  }
}

// ---------------- gsum (blocks 0..2047) + uq/vkv small gemv (2048..2063) ----------------
__global__ __launch_bounds__(256) void k_gsumv(const float* __restrict__ part,
                                               bf16* __restrict__ G,
                                               const bf16* __restrict__ WT,
                                               const float* __restrict__ s,
                                               float* __restrict__ uq,
                                               float* __restrict__ vkv) {
  const int bx = blockIdx.x, tid = threadIdx.x;
  if (bx < 2048) {
    const size_t S8 = (size_t)8 * 262144;
    const size_t i4 = ((size_t)bx * 256 + tid) * 4;
    const float4 a = *(const float4*)(part + i4);
    const float4 c = *(const float4*)(part + i4 + S8);
    const float4 d = *(const float4*)(part + i4 + 2 * S8);
    const float4 e = *(const float4*)(part + i4 + 3 * S8);
    bf16x4 o;
    o[0] = (bf16)(a.x + c.x + d.x + e.x); o[1] = (bf16)(a.y + c.y + d.y + e.y);
    o[2] = (bf16)(a.z + c.z + d.z + e.z); o[3] = (bf16)(a.w + c.w + d.w + e.w);
    *(bf16x4*)(G + i4) = o;
  } else {
    const int z = bx - 2048;            // 0..15
    const int which = z >> 3, b = z & 7;
    const float* sv = s + b * 512;
    for (int o = tid; o < 512; o += 256) {
      const bf16* row = WT + ((size_t)(which * 512 + o)) * 512;
      float acc = 0.f;
      for (int c = 0; c < 512; c += 8) {
        bf16x8 v = *(const bf16x8*)(row + c);
        const float4 s0 = *(const float4*)(sv + c);
        const float4 s1 = *(const float4*)(sv + c + 4);
        acc += (float)v[0] * s0.x + (float)v[1] * s0.y + (float)v[2] * s0.z +
               (float)v[3] * s0.w + (float)v[4] * s1.x + (float)v[5] * s1.y +
               (float)v[6] * s1.z + (float)v[7] * s1.w;
      }
      (which == 0 ? uq : vkv)[b * 512 + o] = acc;
    }
  }
}

// ---------------- batched small GEMM 512x512x512, bf16 out ----------------
__global__ __launch_bounds__(256) void k_sg64_bf(const bf16* __restrict__ Ab, long a_bs,
                                                 const bf16* __restrict__ Bb, long b_bs,
                                                 bf16* __restrict__ Cb) {
  __shared__ bf16 As[64 * 64], Bs[64 * 64];
  const int b = blockIdx.z;
  const int m0 = blockIdx.y * 64, n0 = blockIdx.x * 64;
  f32x4 acc[2][2];
#pragma unroll
  for (int i = 0; i < 2; ++i)
#pragma unroll
    for (int j = 0; j < 2; ++j) acc[i][j] = (f32x4){0.f, 0.f, 0.f, 0.f};
  gemm64_core(Ab + (size_t)b * a_bs + (size_t)m0 * 512, 512,
              Bb + (size_t)b * b_bs + (size_t)n0 * 512, 512, 8, As, Bs, acc);

  const int lane = threadIdx.x & 63, w = threadIdx.x >> 6;
  const int wr = (w >> 1) * 32, wc = (w & 1) * 32;
  const int rr = (lane >> 4) * 4, cc = lane & 15;
  bf16* dst = Cb + (size_t)b * 262144;
#pragma unroll
  for (int i = 0; i < 2; ++i) {
#pragma unroll
    for (int j = 0; j < 2; ++j) {
      const int gm = m0 + wr + i * 16 + rr;
      const int gn = n0 + wc + j * 16 + cc;
      bf16* p = dst + (size_t)gm * 512 + gn;
      p[0]    = (bf16)acc[i][j][0];
      p[512]  = (bf16)acc[i][j][1];
      p[1024] = (bf16)acc[i][j][2];
      p[1536] = (bf16)acc[i][j][3];
    }
  }
}

// ---------------- batched small GEMM 512x512x512, fp32 out ----------------
__global__ __launch_bounds__(256) void k_sg64_f32(const bf16* __restrict__ Ab, long a_bs,
                                                  const bf16* __restrict__ Bb, long b_bs,
                                                  float* __restrict__ Cb) {
  __shared__ bf16 As[64 * 64], Bs[64 * 64];
  const int b = blockIdx.z;
  const int m0 = blockIdx.y * 64, n0 = blockIdx.x * 64;
  f32x4 acc[2][2];
#pragma unroll
  for (int i = 0; i < 2; ++i)
#pragma unroll
    for (int j = 0; j < 2; ++j) acc[i][j] = (f32x4){0.f, 0.f, 0.f, 0.f};
  gemm64_core(Ab + (size_t)b * a_bs + (size_t)m0 * 512, 512,
              Bb + (size_t)b * b_bs + (size_t)n0 * 512, 512, 8, As, Bs, acc);

  const int lane = threadIdx.x & 63, w = threadIdx.x >> 6;
  const int wr = (w >> 1) * 32, wc = (w & 1) * 32;
  const int rr = (lane >> 4) * 4, cc = lane & 15;
  float* dst = Cb + (size_t)b * 262144;
#pragma unroll
  for (int i = 0; i < 2; ++i) {
#pragma unroll
    for (int j = 0; j < 2; ++j) {
      const int gm = m0 + wr + i * 16 + rr;
      const int gn = n0 + wc + j * 16 + cc;
      float* p = dst + (size_t)gm * 512 + gn;
      p[0]    = acc[i][j][0];
      p[512]  = acc[i][j][1];
      p[1024] = acc[i][j][2];
      p[1536] = acc[i][j][3];
    }
  }
}

// ---------------- softmax (4 rows/block, wave-shuffle) -> attnT + attnbv ----------------
__global__ __launch_bounds__(256) void k_smax(const float* __restrict__ L,
                                              const float* __restrict__ uq,
                                              const float* __restrict__ vkv,
                                              const float* __restrict__ bq,
                                              const float* __restrict__ bk,
                                              const float* __restrict__ bv,
                                              bf16* __restrict__ attnT,
                                              float* __restrict__ attnbv) {
  __shared__ bf16 p[4][512];
  const int tid = threadIdx.x;
  const int w = tid >> 6, l = tid & 63;
  const int blk = blockIdx.x;          // 0..1023, 4 rows each
  const int gr = blk * 4 + w;          // global row
  const int b = gr >> 9, i = gr & 511;
  const int c = l * 8;

  const float r  = uq[b * 512 + i];
  const float q0 = bq[i];
  const float* lp = L + (size_t)gr * 512 + c;
  const float4 l0 = *(const float4*)lp;
  const float4 l1 = *(const float4*)(lp + 4);
  const float4 k0 = *(const float4*)(bk + c);
  const float4 k1 = *(const float4*)(bk + c + 4);
  const float4 g0 = *(const float4*)(vkv + b * 512 + c);
  const float4 g1 = *(const float4*)(vkv + b * 512 + c + 4);
  float v[8];
  v[0] = l0.x + r * k0.x + q0 * (g0.x + 4096.f * k0.x);
  v[1] = l0.y + r * k0.y + q0 * (g0.y + 4096.f * k0.y);
  v[2] = l0.z + r * k0.z + q0 * (g0.z + 4096.f * k0.z);
  v[3] = l0.w + r * k0.w + q0 * (g0.w + 4096.f * k0.w);
  v[4] = l1.x + r * k1.x + q0 * (g1.x + 4096.f * k1.x);
  v[5] = l1.y + r * k1.y + q0 * (g1.y + 4096.f * k1.y);
  v[6] = l1.z + r * k1.z + q0 * (g1.z + 4096.f * k1.z);
  v[7] = l1.w + r * k1.w + q0 * (g1.w + 4096.f * k1.w);

  float mx = v[0];
#pragma unroll
  for (int j = 1; j < 8; ++j) mx = fmaxf(mx, v[j]);
  for (int off = 32; off; off >>= 1) mx = fmaxf(mx, __shfl_xor(mx, off));
  float e[8], sm = 0.f;
#pragma unroll
  for (int j = 0; j < 8; ++j) { e[j] = __expf(v[j] - mx); sm += e[j]; }
  for (int off = 32; off; off >>= 1) sm += __shfl_xor(sm, off);
  const float inv = 1.f / sm;

  const float4 b0 = *(const float4*)(bv + c);
  const float4 b1 = *(const float4*)(bv + c + 4);
  float ab = e[0] * b0.x + e[1] * b0.y + e[2] * b0.z + e[3] * b0.w +
             e[4] * b1.x + e[5] * b1.y + e[6] * b1.z + e[7] * b1.w;
  ab *= inv;
  for (int off = 32; off; off >>= 1) ab += __shfl_xor(ab, off);
  if (l == 0) attnbv[gr] = ab;

  bf16x8 o;
#pragma unroll
  for (int j = 0; j < 8; ++j) o[j] = (bf16)(e[j] * inv);
  *(bf16x8*)(&p[w][c]) = o;
  __syncthreads();

  const int i0 = (blk * 4) & 511;
  for (int n = tid; n < 512; n += 256) {
    bf16x4 t;
    t[0] = p[0][n]; t[1] = p[1][n]; t[2] = p[2][n]; t[3] = p[3][n];
    *(bf16x4*)(attnT + (size_t)b * 262144 + (size_t)n * 512 + i0) = t;
  }
}

// ---------------- final: out = x + Hn CT^T + dv + bp ; xcd==batch grid ----------------
__global__ __launch_bounds__(256) void k_final(const bf16* __restrict__ Hn,
                                               const bf16* __restrict__ CT,
                                               const float* __restrict__ attnbv,
                                               const bf16* __restrict__ WTp,
                                               const float* __restrict__ bp,
                                               const float* __restrict__ x,
                                               float* __restrict__ out) {
  __shared__ bf16 As[128 * 64], Bs[128 * 64];
  __shared__ float abvs[512], dvs[128];
  const int Lb = blockIdx.x;           // 0..1023 ; xcd = Lb%8 = batch
  const int b  = Lb & 7;
  const int idx = Lb >> 3;
  const int m0 = (idx >> 2) * 128;
  const int n0 = (idx & 3) * 128;
  const int tid = threadIdx.x;

  for (int cch = tid; cch < 512; cch += 256)
    abvs[cch] = attnbv[b * 512 + cch];
  __syncthreads();
  if (tid < 128) {                     // dv for columns n0..n0+127
    const bf16* wrow = WTp + (size_t)(n0 + tid) * 512;
    float acc = 0.f;
    for (int k = 0; k < 512; k += 8) {
      bf16x8 v = *(const bf16x8*)(wrow + k);
#pragma unroll
      for (int j = 0; j < 8; ++j) acc += (float)v[j] * abvs[k + j];
    }
    dvs[tid] = acc;
  }

  f32x4 acc[4][4];
#pragma unroll
  for (int i = 0; i < 4; ++i)
#pragma unroll
    for (int j = 0; j < 4; ++j) acc[i][j] = (f32x4){0.f, 0.f, 0.f, 0.f};
  gemm128_core(Hn + ((size_t)(b * 4096 + m0)) * 512, 512,
               CT + (size_t)b * 262144 + (size_t)n0 * 512, 512, 8, As, Bs, acc);

  const int lane = tid & 63, w = tid >> 6;
  const int wr = (w >> 1) * 64, wc = (w & 1) * 64;
  const int rr = (lane >> 4) * 4, cc = lane & 15;
#pragma unroll
  for (int i = 0; i < 4; ++i) {
#pragma unroll
    for (int j = 0; j < 4; ++j) {
      const int gm = m0 + wr + i * 16 + rr;
      const int gn = n0 + wc + j * 16 + cc;
      const float add = dvs[gn - n0] + bp[gn];
#pragma unroll
      for (int jj = 0; jj < 4; ++jj) {
        const size_t off = ((size_t)(b * 4096 + gm + jj)) * 512 + gn;
        out[off] = acc[i][j][jj] + add + x[off];
      }
    }
  }
}

extern "C" void kernel_launch(void* const* d_in, const int* in_sizes, int n_in,
                              void* d_out, int out_size, void* d_ws, size_t ws_size,
                              hipStream_t stream) {
  const float* x   = (const float*)d_in[0];
  const float* wq  = (const float*)d_in[1];
  const float* bq  = (const float*)d_in[2];
  const float* wk  = (const float*)d_in[3];
  const float* bk  = (const float*)d_in[4];
  const float* wv  = (const float*)d_in[5];
  const float* bv  = (const float*)d_in[6];
  const float* wp  = (const float*)d_in[7];
  const float* bp  = (const float*)d_in[8];
  const float* gns = (const float*)d_in[9];
  const float* gnb = (const float*)d_in[10];
  float* out = (float*)d_out;

  const size_t MB = 1ull << 20;
  const size_t KB = 1024;
  char* wsb = (char*)d_ws;
  bf16*   WT     = (bf16*)(wsb);                       // 2 MB
  bf16*   wvb    = (bf16*)(wsb + 2 * MB);              // 512 KB
  float2* stats  = (float2*)(wsb + 2 * MB + 512 * KB);
  float*  s      = (float*)(wsb + 2 * MB + 576 * KB);
  float*  uq     = (float*)(wsb + 2 * MB + 640 * KB);
  float*  vkv    = (float*)(wsb + 2 * MB + 704 * KB);
  float*  attnbv = (float*)(wsb + 2 * MB + 832 * KB);  // 16 KB
  bf16*   Hn     = (bf16*)(wsb + 3 * MB);              // 32 MB
  bf16*   HnT    = (bf16*)(wsb + 35 * MB);             // 32 MB
  float*  part   = (float*)(wsb + 67 * MB);            // 32 MB [4][8][512][512]
  bf16*   attnT  = (bf16*)(wsb + 67 * MB);             // overlay (part dead after gsumv)
  bf16*   T      = (bf16*)(wsb + 71 * MB);
  bf16*   CT     = (bf16*)(wsb + 75 * MB);
  bf16*   G      = (bf16*)(wsb + 99 * MB);             // 4 MB
  bf16*   M1     = (bf16*)(wsb + 103 * MB);            // 4 MB
  float*  L      = (float*)(wsb + 107 * MB);           // 8 MB

  const long S2 = 512 * 512;

  k_prep      <<<dim3(1280),    dim3(256), 0, stream>>>(x, wq, wk, wv, wp, WT, wvb, s, stats);
  k_gnapply_t <<<dim3(512),     dim3(256), 0, stream>>>(x, stats, gns, gnb, Hn, HnT, s);
  k_gram      <<<dim3(320),     dim3(256), 0, stream>>>(HnT, part);
  k_gsumv     <<<dim3(2064),    dim3(256), 0, stream>>>(part, G, WT, s, uq, vkv);
  k_sg64_bf   <<<dim3(8, 8, 8), dim3(256), 0, stream>>>(WT, 0, G, S2, M1);
  k_sg64_f32  <<<dim3(8, 8, 8), dim3(256), 0, stream>>>(M1, S2, WT + (size_t)512 * 512, 0, L);
  k_smax      <<<dim3(1024),    dim3(256), 0, stream>>>(L, uq, vkv, bq, bk, bv, attnT, attnbv);
  k_sg64_bf   <<<dim3(8, 8, 8), dim3(256), 0, stream>>>(WT + (size_t)3 * 512 * 512, 0, attnT, S2, T);
  k_sg64_bf   <<<dim3(8, 8, 8), dim3(256), 0, stream>>>(T, S2, wvb, 0, CT);
  k_final     <<<dim3(1024),    dim3(256), 0, stream>>>(Hn, CT, attnbv, WT + (size_t)3 * 512 * 512,
                                                        bp, x, out);
}

// Round 10
// 181.182 us; speedup vs baseline: 1.5360x; 1.0129x over previous
//
#include <hip/hip_runtime.h>
#include <hip/hip_bf16.h>

// SelfAttention (channel attention) on MI355X. Inputs fp32, OUTPUT fp32.
//   Hn = GN(x) (bf16, row-major + transposed HnT)
//   G_b = Hn_b^T Hn_b ; L_b = Wq^T G_b Wk + rank-1 bias terms
//   attn_b = softmax_rows(L_b) ; attnbv[k] = attn_b[k,:]·bv
//   CT_b = (Wp^T attn_b) Wv^T ; dv = Wp^T attnbv
//   out = x + Hn CT_b^T + dv + bp
// R10: k_final latency-bound at 18% occupancy (52us, 11% MfmaUtil, 38% HBM).
//      -> 128x64 tiles, 2048 blocks (8/CU), LDS 26KB, ~6 resident blocks/CU.
// Workspace: unchanged from R8/R9.

using bf16   = __bf16;
using bf16x8 = __attribute__((ext_vector_type(8))) __bf16;
using bf16x4 = __attribute__((ext_vector_type(4))) __bf16;
using f32x4  = __attribute__((ext_vector_type(4))) float;

#define DI __device__ __forceinline__

DI void gload16(const bf16* g, bf16* l) {
  __builtin_amdgcn_global_load_lds(
      (const __attribute__((address_space(1))) void*)g,
      (__attribute__((address_space(3))) void*)l, 16, 0, 0);
}

// ---------------- 128x128 tile core: gload_lds staging + XOR-swizzled reads ----
DI void gemm128_core(const bf16* __restrict__ A, long lda,
                     const bf16* __restrict__ B, long ldb,
                     int ksteps, bf16* As, bf16* Bs, f32x4 acc[4][4]) {
  const int tid  = threadIdx.x;
  const int lane = tid & 63;
  const int w    = tid >> 6;
  const int lr   = lane & 15;
  const int lk   = (lane >> 4) * 8;
  const int wr   = (w >> 1) * 64;
  const int wc   = (w & 1) * 64;
  const int sw   = (lr & 7) << 3;

  const int  srow = lane >> 3;                       // 0..7
  const int  ssw  = ((lane & 7) ^ srow) << 3;        // pre-swizzled col
  const bf16* ga = A + (long)(w * 8 + srow) * lda + ssw;
  const bf16* gb = B + (long)(w * 8 + srow) * ldb + ssw;
  bf16* lA = As + w * 512;                           // wave-uniform LDS base
  bf16* lB = Bs + w * 512;

  for (int kt = 0; kt < ksteps; ++kt) {
#pragma unroll
    for (int c = 0; c < 4; ++c) {
      gload16(ga + (long)c * 32 * lda, lA + c * 2048);
      gload16(gb + (long)c * 32 * ldb, lB + c * 2048);
    }
    ga += 64; gb += 64;
    __syncthreads();
#pragma unroll
    for (int kk = 0; kk < 2; ++kk) {
      bf16x8 af[4], bfr[4];
#pragma unroll
      for (int i = 0; i < 4; ++i)
        af[i] = *(const bf16x8*)(As + (wr + i * 16 + lr) * 64 + ((kk * 32 + lk) ^ sw));
#pragma unroll
      for (int i = 0; i < 4; ++i)
        bfr[i] = *(const bf16x8*)(Bs + (wc + i * 16 + lr) * 64 + ((kk * 32 + lk) ^ sw));
#pragma unroll
      for (int i = 0; i < 4; ++i)
#pragma unroll
        for (int j = 0; j < 4; ++j)
          acc[i][j] = __builtin_amdgcn_mfma_f32_16x16x32_bf16(af[i], bfr[j], acc[i][j], 0, 0, 0);
    }
    __syncthreads();
  }
}

// ---------------- 128x64 tile core (k_final): more blocks, less LDS ----------
DI void gemm128x64_core(const bf16* __restrict__ A, long lda,
                        const bf16* __restrict__ B, long ldb,
                        int ksteps, bf16* As, bf16* Bs, f32x4 acc[4][2]) {
  const int tid  = threadIdx.x;
  const int lane = tid & 63;
  const int w    = tid >> 6;
  const int lr   = lane & 15;
  const int lk   = (lane >> 4) * 8;
  const int wr   = (w >> 1) * 64;      // M-half
  const int wc   = (w & 1) * 32;       // N-half
  const int sw   = (lr & 7) << 3;

  const int  srow = lane >> 3;
  const int  ssw  = ((lane & 7) ^ srow) << 3;
  const bf16* ga = A + (long)(w * 8 + srow) * lda + ssw;
  const bf16* gb = B + (long)(w * 8 + srow) * ldb + ssw;
  bf16* lA = As + w * 512;
  bf16* lB = Bs + w * 512;

  for (int kt = 0; kt < ksteps; ++kt) {
#pragma unroll
    for (int c = 0; c < 4; ++c)
      gload16(ga + (long)c * 32 * lda, lA + c * 2048);
#pragma unroll
    for (int c = 0; c < 2; ++c)
      gload16(gb + (long)c * 32 * ldb, lB + c * 2048);
    ga += 64; gb += 64;
    __syncthreads();
#pragma unroll
    for (int kk = 0; kk < 2; ++kk) {
      bf16x8 af[4], bfr[2];
#pragma unroll
      for (int i = 0; i < 4; ++i)
        af[i] = *(const bf16x8*)(As + (wr + i * 16 + lr) * 64 + ((kk * 32 + lk) ^ sw));
#pragma unroll
      for (int j = 0; j < 2; ++j)
        bfr[j] = *(const bf16x8*)(Bs + (wc + j * 16 + lr) * 64 + ((kk * 32 + lk) ^ sw));
#pragma unroll
      for (int i = 0; i < 4; ++i)
#pragma unroll
        for (int j = 0; j < 2; ++j)
          acc[i][j] = __builtin_amdgcn_mfma_f32_16x16x32_bf16(af[i], bfr[j], acc[i][j], 0, 0, 0);
    }
    __syncthreads();
  }
}

// ---------------- 64x64 tile core ----------------
DI void gemm64_core(const bf16* __restrict__ A, long lda,
                    const bf16* __restrict__ B, long ldb,
                    int ksteps, bf16* As, bf16* Bs, f32x4 acc[2][2]) {
  const int tid  = threadIdx.x;
  const int lane = tid & 63;
  const int w    = tid >> 6;
  const int lr   = lane & 15;
  const int lk   = (lane >> 4) * 8;
  const int wr   = (w >> 1) * 32;
  const int wc   = (w & 1) * 32;
  const int sw   = (lr & 7) << 3;

  const int  srow = lane >> 3;
  const int  ssw  = ((lane & 7) ^ srow) << 3;
  const bf16* ga = A + (long)(w * 8 + srow) * lda + ssw;
  const bf16* gb = B + (long)(w * 8 + srow) * ldb + ssw;
  bf16* lA = As + w * 512;
  bf16* lB = Bs + w * 512;

  for (int kt = 0; kt < ksteps; ++kt) {
#pragma unroll
    for (int c = 0; c < 2; ++c) {
      gload16(ga + (long)c * 32 * lda, lA + c * 2048);
      gload16(gb + (long)c * 32 * ldb, lB + c * 2048);
    }
    ga += 64; gb += 64;
    __syncthreads();
#pragma unroll
    for (int kk = 0; kk < 2; ++kk) {
      bf16x8 af[2], bfr[2];
#pragma unroll
      for (int i = 0; i < 2; ++i)
        af[i] = *(const bf16x8*)(As + (wr + i * 16 + lr) * 64 + ((kk * 32 + lk) ^ sw));
#pragma unroll
      for (int i = 0; i < 2; ++i)
        bfr[i] = *(const bf16x8*)(Bs + (wc + i * 16 + lr) * 64 + ((kk * 32 + lk) ^ sw));
#pragma unroll
      for (int i = 0; i < 2; ++i)
#pragma unroll
        for (int j = 0; j < 2; ++j)
          acc[i][j] = __builtin_amdgcn_mfma_f32_16x16x32_bf16(af[i], bfr[j], acc[i][j], 0, 0, 0);
    }
    __syncthreads();
  }
}

// ---------------- prep: GN stats (blocks 0..255) + weight transpose (256..1279) ----------------
__global__ __launch_bounds__(256) void k_prep(const float* __restrict__ x,
                                              const float* __restrict__ wq,
                                              const float* __restrict__ wk,
                                              const float* __restrict__ wv,
                                              const float* __restrict__ wp,
                                              bf16* __restrict__ WT,
                                              bf16* __restrict__ wvb,
                                              float* __restrict__ s,
                                              float2* __restrict__ stats) {
  __shared__ float shm[1056];
  const int tid = threadIdx.x;
  const int bx = blockIdx.x;
  if (bx < 256) {
    const int b = bx >> 5, g = bx & 31;
    const float* base = x + (size_t)b * 4096 * 512 + g * 16;
    float sm = 0.f, ss = 0.f;
    for (int it = 0; it < 64; ++it) {
      const int idx = it * 256 + tid;
      const int p = idx >> 2, c4 = (idx & 3) * 4;
      float4 v = *(const float4*)(base + (size_t)p * 512 + c4);
      sm += v.x + v.y + v.z + v.w;
      ss += v.x * v.x + v.y * v.y + v.z * v.z + v.w * v.w;
    }
    float* rs = shm; float* rss = shm + 256;
    rs[tid] = sm; rss[tid] = ss; __syncthreads();
    for (int off = 128; off; off >>= 1) {
      if (tid < off) { rs[tid] += rs[tid + off]; rss[tid] += rss[tid + off]; }
      __syncthreads();
    }
    if (tid == 0) {
      float mean = rs[0] * (1.f / 65536.f);
      float var  = rss[0] * (1.f / 65536.f) - mean * mean;
      stats[bx] = float2{mean, rsqrtf(var + 1e-5f)};
    }
  } else {
    const int r = bx - 256;             // 0..1023
    const int z = r >> 8;
    const int r2 = r & 255;
    const int bxx = r2 & 15, byy = r2 >> 4;
    const int tx = tid & 31, ty = tid >> 5;
    const float* src = (z == 0) ? wq : (z == 1) ? wk : (z == 2) ? wv : wp;
    const int n0 = bxx * 32, k0 = byy * 32;
    if (z == 0 && byy == 0) s[bxx * 256 + tid] = 0.f;
#pragma unroll
    for (int j = 0; j < 4; ++j) {
      const float v = src[(size_t)(k0 + ty + j * 8) * 512 + n0 + tx];
      shm[(ty + j * 8) * 33 + tx] = v;
      if (z == 2) wvb[(size_t)(k0 + ty + j * 8) * 512 + n0 + tx] = (bf16)v;
    }
    __syncthreads();
#pragma unroll
    for (int j = 0; j < 4; ++j)
      WT[(size_t)(z * 512 + n0 + ty + j * 8) * 512 + k0 + tx] = (bf16)shm[tx * 33 + ty + j * 8];
  }
}

// ---------------- GN apply -> Hn + HnT + col-sums s ----------------
__global__ __launch_bounds__(256) void k_gnapply_t(const float* __restrict__ x,
                                                   const float2* __restrict__ stats,
                                                   const float* __restrict__ gns,
                                                   const float* __restrict__ gnb,
                                                   bf16* __restrict__ Hn,
                                                   bf16* __restrict__ HnT,
                                                   float* __restrict__ s) {
  __shared__ bf16 tile[64 * 516];
  __shared__ float cs[512];
  const int tid = threadIdx.x;
  const int blk = blockIdx.x;       // 0..511
  const int b = blk >> 6, p0 = (blk & 63) * 64;
  cs[tid] = 0.f; cs[tid + 256] = 0.f;
  __syncthreads();

  const int c4 = (tid & 127) * 4;
  const int hi = tid >> 7;
  const float2 st = stats[b * 32 + (c4 >> 4)];
  const float4 sc = *(const float4*)(gns + c4);
  const float4 bi = *(const float4*)(gnb + c4);
  float a0 = 0.f, a1 = 0.f, a2 = 0.f, a3 = 0.f;
  for (int i = 0; i < 32; ++i) {
    const int px = i * 2 + hi;
    const float4 xv = *(const float4*)(x + ((size_t)(b * 4096 + p0 + px)) * 512 + c4);
    const float h0 = (xv.x - st.x) * st.y * sc.x + bi.x;
    const float h1 = (xv.y - st.x) * st.y * sc.y + bi.y;
    const float h2 = (xv.z - st.x) * st.y * sc.z + bi.z;
    const float h3 = (xv.w - st.x) * st.y * sc.w + bi.w;
    a0 += h0; a1 += h1; a2 += h2; a3 += h3;
    bf16x4 hv;
    hv[0] = (bf16)h0; hv[1] = (bf16)h1; hv[2] = (bf16)h2; hv[3] = (bf16)h3;
    *(bf16x4*)(Hn + ((size_t)(b * 4096 + p0 + px)) * 512 + c4) = hv;
    *(bf16x4*)(tile + px * 516 + c4) = hv;
  }
  atomicAdd(&cs[c4 + 0], a0); atomicAdd(&cs[c4 + 1], a1);
  atomicAdd(&cs[c4 + 2], a2); atomicAdd(&cs[c4 + 3], a3);
  __syncthreads();
  atomicAdd(s + b * 512 + tid, cs[tid]);
  atomicAdd(s + b * 512 + 256 + tid, cs[tid + 256]);

  for (int cg = 0; cg < 16; ++cg) {
    const int c  = cg * 32 + (tid >> 3);
    const int so = (tid & 7) * 8;
    bf16x8 pk;
#pragma unroll
    for (int k = 0; k < 8; ++k) pk[k] = tile[(so + k) * 516 + c];
    *(bf16x8*)(HnT + ((size_t)(b * 512 + c)) * 4096 + p0 + so) = pk;
  }
}

// ---------------- Gram: symmetric tiles, split-K=4, xcd==batch ----------------
__global__ __launch_bounds__(256) void k_gram(const bf16* __restrict__ HnT,
                                              float* __restrict__ part) {
  __shared__ bf16 As[128 * 64], Bs[128 * 64];
  const int Lb = blockIdx.x;           // 0..319 ; xcd = Lb%8 = batch
  const int b  = Lb & 7;
  const int idx = Lb >> 3;             // 0..39
  const int sp = idx & 3;
  const int t  = idx >> 2;             // 0..9 upper-tri tile id
  const int m0 = (int)((0x3221110000ull >> (4 * t)) & 15) * 128;
  const int n0 = (int)((0x3323213210ull >> (4 * t)) & 15) * 128;
  f32x4 acc[4][4];
#pragma unroll
  for (int i = 0; i < 4; ++i)
#pragma unroll
    for (int j = 0; j < 4; ++j) acc[i][j] = (f32x4){0.f, 0.f, 0.f, 0.f};
  const bf16* A = HnT + ((size_t)b * 512 + m0) * 4096 + sp * 1024;
  const bf16* B = HnT + ((size_t)b * 512 + n0) * 4096 + sp * 1024;
  gemm128_core(A, 4096, B, 4096, 16, As, Bs, acc);

  const int lane = threadIdx.x & 63, w = threadIdx.x >> 6;
  const int wr = (w >> 1) * 64, wc = (w & 1) * 64;
  const int rr = (lane >> 4) * 4, cc = lane & 15;
  float* dst = part + (size_t)(sp * 8 + b) * 262144;
#pragma unroll
  for (int i = 0; i < 4; ++i) {
#pragma unroll
    for (int j = 0; j < 4; ++j) {
      const int gm = m0 + wr + i * 16 + rr;
      const int gn = n0 + wc + j * 16 + cc;
      float* p = dst + (size_t)gm * 512 + gn;
      p[0]    = acc[i][j][0];
      p[512]  = acc[i][j][1];
      p[1024] = acc[i][j][2];
      p[1536] = acc[i][j][3];
      if (m0 != n0)
        *(f32x4*)(dst + (size_t)gn * 512 + gm) = acc[i][j];
    }
  }
}

// ---------------- gsum (blocks 0..2047) + uq/vkv small gemv (2048..2063) ----------------
__global__ __launch_bounds__(256) void k_gsumv(const float* __restrict__ part,
                                               bf16* __restrict__ G,
                                               const bf16* __restrict__ WT,
                                               const float* __restrict__ s,
                                               float* __restrict__ uq,
                                               float* __restrict__ vkv) {
  const int bx = blockIdx.x, tid = threadIdx.x;
  if (bx < 2048) {
    const size_t S8 = (size_t)8 * 262144;
    const size_t i4 = ((size_t)bx * 256 + tid) * 4;
    const float4 a = *(const float4*)(part + i4);
    const float4 c = *(const float4*)(part + i4 + S8);
    const float4 d = *(const float4*)(part + i4 + 2 * S8);
    const float4 e = *(const float4*)(part + i4 + 3 * S8);
    bf16x4 o;
    o[0] = (bf16)(a.x + c.x + d.x + e.x); o[1] = (bf16)(a.y + c.y + d.y + e.y);
    o[2] = (bf16)(a.z + c.z + d.z + e.z); o[3] = (bf16)(a.w + c.w + d.w + e.w);
    *(bf16x4*)(G + i4) = o;
  } else {
    const int z = bx - 2048;            // 0..15
    const int which = z >> 3, b = z & 7;
    const float* sv = s + b * 512;
    for (int o = tid; o < 512; o += 256) {
      const bf16* row = WT + ((size_t)(which * 512 + o)) * 512;
      float acc = 0.f;
      for (int c = 0; c < 512; c += 8) {
        bf16x8 v = *(const bf16x8*)(row + c);
        const float4 s0 = *(const float4*)(sv + c);
        const float4 s1 = *(const float4*)(sv + c + 4);
        acc += (float)v[0] * s0.x + (float)v[1] * s0.y + (float)v[2] * s0.z +
               (float)v[3] * s0.w + (float)v[4] * s1.x + (float)v[5] * s1.y +
               (float)v[6] * s1.z + (float)v[7] * s1.w;
      }
      (which == 0 ? uq : vkv)[b * 512 + o] = acc;
    }
  }
}

// ---------------- batched small GEMM 512x512x512, bf16 out ----------------
__global__ __launch_bounds__(256) void k_sg64_bf(const bf16* __restrict__ Ab, long a_bs,
                                                 const bf16* __restrict__ Bb, long b_bs,
                                                 bf16* __restrict__ Cb) {
  __shared__ bf16 As[64 * 64], Bs[64 * 64];
  const int b = blockIdx.z;
  const int m0 = blockIdx.y * 64, n0 = blockIdx.x * 64;
  f32x4 acc[2][2];
#pragma unroll
  for (int i = 0; i < 2; ++i)
#pragma unroll
    for (int j = 0; j < 2; ++j) acc[i][j] = (f32x4){0.f, 0.f, 0.f, 0.f};
  gemm64_core(Ab + (size_t)b * a_bs + (size_t)m0 * 512, 512,
              Bb + (size_t)b * b_bs + (size_t)n0 * 512, 512, 8, As, Bs, acc);

  const int lane = threadIdx.x & 63, w = threadIdx.x >> 6;
  const int wr = (w >> 1) * 32, wc = (w & 1) * 32;
  const int rr = (lane >> 4) * 4, cc = lane & 15;
  bf16* dst = Cb + (size_t)b * 262144;
#pragma unroll
  for (int i = 0; i < 2; ++i) {
#pragma unroll
    for (int j = 0; j < 2; ++j) {
      const int gm = m0 + wr + i * 16 + rr;
      const int gn = n0 + wc + j * 16 + cc;
      bf16* p = dst + (size_t)gm * 512 + gn;
      p[0]    = (bf16)acc[i][j][0];
      p[512]  = (bf16)acc[i][j][1];
      p[1024] = (bf16)acc[i][j][2];
      p[1536] = (bf16)acc[i][j][3];
    }
  }
}

// ---------------- batched small GEMM 512x512x512, fp32 out ----------------
__global__ __launch_bounds__(256) void k_sg64_f32(const bf16* __restrict__ Ab, long a_bs,
                                                  const bf16* __restrict__ Bb, long b_bs,
                                                  float* __restrict__ Cb) {
  __shared__ bf16 As[64 * 64], Bs[64 * 64];
  const int b = blockIdx.z;
  const int m0 = blockIdx.y * 64, n0 = blockIdx.x * 64;
  f32x4 acc[2][2];
#pragma unroll
  for (int i = 0; i < 2; ++i)
#pragma unroll
    for (int j = 0; j < 2; ++j) acc[i][j] = (f32x4){0.f, 0.f, 0.f, 0.f};
  gemm64_core(Ab + (size_t)b * a_bs + (size_t)m0 * 512, 512,
              Bb + (size_t)b * b_bs + (size_t)n0 * 512, 512, 8, As, Bs, acc);

  const int lane = threadIdx.x & 63, w = threadIdx.x >> 6;
  const int wr = (w >> 1) * 32, wc = (w & 1) * 32;
  const int rr = (lane >> 4) * 4, cc = lane & 15;
  float* dst = Cb + (size_t)b * 262144;
#pragma unroll
  for (int i = 0; i < 2; ++i) {
#pragma unroll
    for (int j = 0; j < 2; ++j) {
      const int gm = m0 + wr + i * 16 + rr;
      const int gn = n0 + wc + j * 16 + cc;
      float* p = dst + (size_t)gm * 512 + gn;
      p[0]    = acc[i][j][0];
      p[512]  = acc[i][j][1];
      p[1024] = acc[i][j][2];
      p[1536] = acc[i][j][3];
    }
  }
}

// ---------------- softmax (4 rows/block, wave-shuffle) -> attnT + attnbv ----------------
__global__ __launch_bounds__(256) void k_smax(const float* __restrict__ L,
                                              const float* __restrict__ uq,
                                              const float* __restrict__ vkv,
                                              const float* __restrict__ bq,
                                              const float* __restrict__ bk,
                                              const float* __restrict__ bv,
                                              bf16* __restrict__ attnT,
                                              float* __restrict__ attnbv) {
  __shared__ bf16 p[4][512];
  const int tid = threadIdx.x;
  const int w = tid >> 6, l = tid & 63;
  const int blk = blockIdx.x;          // 0..1023, 4 rows each
  const int gr = blk * 4 + w;          // global row
  const int b = gr >> 9, i = gr & 511;
  const int c = l * 8;

  const float r  = uq[b * 512 + i];
  const float q0 = bq[i];
  const float* lp = L + (size_t)gr * 512 + c;
  const float4 l0 = *(const float4*)lp;
  const float4 l1 = *(const float4*)(lp + 4);
  const float4 k0 = *(const float4*)(bk + c);
  const float4 k1 = *(const float4*)(bk + c + 4);
  const float4 g0 = *(const float4*)(vkv + b * 512 + c);
  const float4 g1 = *(const float4*)(vkv + b * 512 + c + 4);
  float v[8];
  v[0] = l0.x + r * k0.x + q0 * (g0.x + 4096.f * k0.x);
  v[1] = l0.y + r * k0.y + q0 * (g0.y + 4096.f * k0.y);
  v[2] = l0.z + r * k0.z + q0 * (g0.z + 4096.f * k0.z);
  v[3] = l0.w + r * k0.w + q0 * (g0.w + 4096.f * k0.w);
  v[4] = l1.x + r * k1.x + q0 * (g1.x + 4096.f * k1.x);
  v[5] = l1.y + r * k1.y + q0 * (g1.y + 4096.f * k1.y);
  v[6] = l1.z + r * k1.z + q0 * (g1.z + 4096.f * k1.z);
  v[7] = l1.w + r * k1.w + q0 * (g1.w + 4096.f * k1.w);

  float mx = v[0];
#pragma unroll
  for (int j = 1; j < 8; ++j) mx = fmaxf(mx, v[j]);
  for (int off = 32; off; off >>= 1) mx = fmaxf(mx, __shfl_xor(mx, off));
  float e[8], sm = 0.f;
#pragma unroll
  for (int j = 0; j < 8; ++j) { e[j] = __expf(v[j] - mx); sm += e[j]; }
  for (int off = 32; off; off >>= 1) sm += __shfl_xor(sm, off);
  const float inv = 1.f / sm;

  const float4 b0 = *(const float4*)(bv + c);
  const float4 b1 = *(const float4*)(bv + c + 4);
  float ab = e[0] * b0.x + e[1] * b0.y + e[2] * b0.z + e[3] * b0.w +
             e[4] * b1.x + e[5] * b1.y + e[6] * b1.z + e[7] * b1.w;
  ab *= inv;
  for (int off = 32; off; off >>= 1) ab += __shfl_xor(ab, off);
  if (l == 0) attnbv[gr] = ab;

  bf16x8 o;
#pragma unroll
  for (int j = 0; j < 8; ++j) o[j] = (bf16)(e[j] * inv);
  *(bf16x8*)(&p[w][c]) = o;
  __syncthreads();

  const int i0 = (blk * 4) & 511;
  for (int n = tid; n < 512; n += 256) {
    bf16x4 t;
    t[0] = p[0][n]; t[1] = p[1][n]; t[2] = p[2][n]; t[3] = p[3][n];
    *(bf16x4*)(attnT + (size_t)b * 262144 + (size_t)n * 512 + i0) = t;
  }
}

// ---------------- final: out = x + Hn CT^T + dv + bp ; 128x64 tiles, xcd==batch ----------------
__global__ __launch_bounds__(256) void k_final(const bf16* __restrict__ Hn,
                                               const bf16* __restrict__ CT,
                                               const float* __restrict__ attnbv,
                                               const bf16* __restrict__ WTp,
                                               const float* __restrict__ bp,
                                               const float* __restrict__ x,
                                               float* __restrict__ out) {
  __shared__ bf16 As[128 * 64], Bs[64 * 64];
  __shared__ float abvs[512], dvs[64];
  const int Lb = blockIdx.x;           // 0..2047 ; xcd = Lb%8 = batch
  const int b  = Lb & 7;
  const int idx = Lb >> 3;             // 0..255
  const int m0 = (idx >> 3) * 128;     // 32 M-tiles
  const int n0 = (idx & 7) * 64;       // 8 N-tiles
  const int tid = threadIdx.x;

  for (int cch = tid; cch < 512; cch += 256)
    abvs[cch] = attnbv[b * 512 + cch];
  __syncthreads();
  if (tid < 64) {                      // dv for columns n0..n0+63
    const bf16* wrow = WTp + (size_t)(n0 + tid) * 512;
    float acc = 0.f;
    for (int k = 0; k < 512; k += 8) {
      bf16x8 v = *(const bf16x8*)(wrow + k);
#pragma unroll
      for (int j = 0; j < 8; ++j) acc += (float)v[j] * abvs[k + j];
    }
    dvs[tid] = acc;
  }

  f32x4 acc[4][2];
#pragma unroll
  for (int i = 0; i < 4; ++i)
#pragma unroll
    for (int j = 0; j < 2; ++j) acc[i][j] = (f32x4){0.f, 0.f, 0.f, 0.f};
  gemm128x64_core(Hn + ((size_t)(b * 4096 + m0)) * 512, 512,
                  CT + (size_t)b * 262144 + (size_t)n0 * 512, 512, 8, As, Bs, acc);

  const int lane = tid & 63, w = tid >> 6;
  const int wr = (w >> 1) * 64, wc = (w & 1) * 32;
  const int rr = (lane >> 4) * 4, cc = lane & 15;
#pragma unroll
  for (int i = 0; i < 4; ++i) {
#pragma unroll
    for (int j = 0; j < 2; ++j) {
      const int gm = m0 + wr + i * 16 + rr;
      const int gn = n0 + wc + j * 16 + cc;
      const float add = dvs[gn - n0] + bp[gn];
#pragma unroll
      for (int jj = 0; jj < 4; ++jj) {
        const size_t off = ((size_t)(b * 4096 + gm + jj)) * 512 + gn;
        out[off] = acc[i][j][jj] + add + x[off];
      }
    }
  }
}

extern "C" void kernel_launch(void* const* d_in, const int* in_sizes, int n_in,
                              void* d_out, int out_size, void* d_ws, size_t ws_size,
                              hipStream_t stream) {
  const float* x   = (const float*)d_in[0];
  const float* wq  = (const float*)d_in[1];
  const float* bq  = (const float*)d_in[2];
  const float* wk  = (const float*)d_in[3];
  const float* bk  = (const float*)d_in[4];
  const float* wv  = (const float*)d_in[5];
  const float* bv  = (const float*)d_in[6];
  const float* wp  = (const float*)d_in[7];
  const float* bp  = (const float*)d_in[8];
  const float* gns = (const float*)d_in[9];
  const float* gnb = (const float*)d_in[10];
  float* out = (float*)d_out;

  const size_t MB = 1ull << 20;
  const size_t KB = 1024;
  char* wsb = (char*)d_ws;
  bf16*   WT     = (bf16*)(wsb);                       // 2 MB
  bf16*   wvb    = (bf16*)(wsb + 2 * MB);              // 512 KB
  float2* stats  = (float2*)(wsb + 2 * MB + 512 * KB);
  float*  s      = (float*)(wsb + 2 * MB + 576 * KB);
  float*  uq     = (float*)(wsb + 2 * MB + 640 * KB);
  float*  vkv    = (float*)(wsb + 2 * MB + 704 * KB);
  float*  attnbv = (float*)(wsb + 2 * MB + 832 * KB);  // 16 KB
  bf16*   Hn     = (bf16*)(wsb + 3 * MB);              // 32 MB
  bf16*   HnT    = (bf16*)(wsb + 35 * MB);             // 32 MB
  float*  part   = (float*)(wsb + 67 * MB);            // 32 MB [4][8][512][512]
  bf16*   attnT  = (bf16*)(wsb + 67 * MB);             // overlay (part dead after gsumv)
  bf16*   T      = (bf16*)(wsb + 71 * MB);
  bf16*   CT     = (bf16*)(wsb + 75 * MB);
  bf16*   G      = (bf16*)(wsb + 99 * MB);             // 4 MB
  bf16*   M1     = (bf16*)(wsb + 103 * MB);            // 4 MB
  float*  L      = (float*)(wsb + 107 * MB);           // 8 MB

  const long S2 = 512 * 512;

  k_prep      <<<dim3(1280),    dim3(256), 0, stream>>>(x, wq, wk, wv, wp, WT, wvb, s, stats);
  k_gnapply_t <<<dim3(512),     dim3(256), 0, stream>>>(x, stats, gns, gnb, Hn, HnT, s);
  k_gram      <<<dim3(320),     dim3(256), 0, stream>>>(HnT, part);
  k_gsumv     <<<dim3(2064),    dim3(256), 0, stream>>>(part, G, WT, s, uq, vkv);
  k_sg64_bf   <<<dim3(8, 8, 8), dim3(256), 0, stream>>>(WT, 0, G, S2, M1);
  k_sg64_f32  <<<dim3(8, 8, 8), dim3(256), 0, stream>>>(M1, S2, WT + (size_t)512 * 512, 0, L);
  k_smax      <<<dim3(1024),    dim3(256), 0, stream>>>(L, uq, vkv, bq, bk, bv, attnT, attnbv);
  k_sg64_bf   <<<dim3(8, 8, 8), dim3(256), 0, stream>>>(WT + (size_t)3 * 512 * 512, 0, attnT, S2, T);
  k_sg64_bf   <<<dim3(8, 8, 8), dim3(256), 0, stream>>>(T, S2, wvb, 0, CT);
  k_final     <<<dim3(2048),    dim3(256), 0, stream>>>(Hn, CT, attnbv, WT + (size_t)3 * 512 * 512,
                                                        bp, x, out);
}